// Round 4
// baseline (491.904 us; speedup 1.0000x reference)
//
#include <hip/hip_runtime.h>
#include <hip/hip_fp16.h>

constexpr int C = 128;
constexpr int N = 4096;
constexpr int B = 4;

typedef _Float16 f16x8 __attribute__((ext_vector_type(8)));
typedef _Float16 f16x4 __attribute__((ext_vector_type(4)));
typedef float    f32x4 __attribute__((ext_vector_type(4)));

// ---------------------------------------------------------------------------
// One-shot weight convert fp32 -> f16 into workspace, concatenated:
// [w1(16K) | w2(16K) | wv(64K) | wt(64K) | wqk(16K)] elements.
// grid 176, 256 thr; each thread converts one float4.
// ---------------------------------------------------------------------------
__global__ __launch_bounds__(256) void k_wcvt(const float* __restrict__ w1,
                                              const float* __restrict__ w2,
                                              const float* __restrict__ wv,
                                              const float* __restrict__ wt,
                                              const float* __restrict__ wqk,
                                              _Float16* __restrict__ WF) {
  const int g = blockIdx.x * 256 + threadIdx.x;   // float4 index
  const float* src; int off;
  if (g < 4096)       { src = w1;  off = g; }
  else if (g < 8192)  { src = w2;  off = g - 4096; }
  else if (g < 24576) { src = wv;  off = g - 8192; }
  else if (g < 40960) { src = wt;  off = g - 24576; }
  else                { src = wqk; off = g - 40960; }
  const float4 v = ((const float4*)src)[off];
  f16x4 h = {(_Float16)v.x, (_Float16)v.y, (_Float16)v.z, (_Float16)v.w};
  *(f16x4*)&WF[(size_t)g * 4] = h;
}

// ---------------------------------------------------------------------------
// Mask compaction: exclusive prefix sum of (mask!=0) per batch + valid count.
// grid B, 1024 thr (4 elements/thread).
// ---------------------------------------------------------------------------
__global__ __launch_bounds__(1024) void k_mask(const int* __restrict__ mask,
                                               int* __restrict__ psum,
                                               int* __restrict__ nvb) {
  const int b = blockIdx.x, tid = threadIdx.x;
  __shared__ int wsum[16];
  const int4 mv = *(const int4*)&mask[b * N + tid * 4];
  const int m0 = (mv.x != 0), m1 = (mv.y != 0), m2 = (mv.z != 0), m3 = (mv.w != 0);
  const int s0 = m0, s1 = s0 + m1, s2 = s1 + m2, s3 = s2 + m3;
  const int lane = tid & 63, w = tid >> 6;
  int sc = s3;
#pragma unroll
  for (int o = 1; o < 64; o <<= 1) {
    const int v = __shfl_up(sc, o, 64);
    if (lane >= o) sc += v;
  }
  if (lane == 63) wsum[w] = sc;
  __syncthreads();
  if (tid < 16) {
    int v = wsum[tid];
#pragma unroll
    for (int o = 1; o < 16; o <<= 1) {
      const int u = __shfl_up(v, o, 64);
      if (tid >= o) v += u;
    }
    wsum[tid] = v;
  }
  __syncthreads();
  const int excl = ((w > 0) ? wsum[w - 1] : 0) + sc - s3;
  int4 pv;
  pv.x = excl; pv.y = excl + s0; pv.z = excl + s1; pv.w = excl + s2;
  *(int4*)&psum[b * N + tid * 4] = pv;
  if (tid == 0) nvb[b] = wsum[15];
}

// ---------------------------------------------------------------------------
// MFMA projection GEMM. Y[b,o,n] = sum_c W[o,c]*X[b,c,n] (+bias), fp32 out.
// grid (N/64, 2, B), block 512.
// ---------------------------------------------------------------------------
template<bool BIAS, bool STAT>
__global__ __launch_bounds__(512) void k_gwm(const _Float16* __restrict__ WF,
                                             const float* __restrict__ X,
                                             const float* __restrict__ bias,
                                             float* __restrict__ Y,
                                             float* __restrict__ bnpart) {
  __shared__ _Float16 XT[64 * 136];          // [n][c], stride 136 (16B-aligned rows)
  __shared__ float statP[4][64], statQ[4][64];
  const int tid = threadIdx.x;
  const int n0 = blockIdx.x * 64, oh = blockIdx.y, b = blockIdx.z;
  const float* Xb = X + (size_t)(b * C) * N + n0;
#pragma unroll
  for (int i = 0; i < 4; i++) {              // 2048 float4: c=idx>>4, q=idx&15
    const int idx = tid + i * 512;
    const int c = idx >> 4, q = idx & 15;
    const float4 v = *(const float4*)&Xb[(size_t)c * N + q * 4];
    XT[(q * 4 + 0) * 136 + c] = (_Float16)v.x;
    XT[(q * 4 + 1) * 136 + c] = (_Float16)v.y;
    XT[(q * 4 + 2) * 136 + c] = (_Float16)v.z;
    XT[(q * 4 + 3) * 136 + c] = (_Float16)v.w;
  }
  __syncthreads();
  const int w = tid >> 6, lane = tid & 63, quad = lane >> 4, lr = lane & 15;
  const int nt = w & 3, og = w >> 2;
  const int ob[2] = {oh * 64 + og * 16, oh * 64 + (og + 2) * 16};
  f16x8 aW[2][4];
#pragma unroll
  for (int t = 0; t < 2; t++)
#pragma unroll
    for (int kc = 0; kc < 4; kc++)
      aW[t][kc] = *(const f16x8*)&WF[(size_t)(ob[t] + lr) * 128 + kc * 32 + quad * 8];
  f32x4 acc[2];
  acc[0] = (f32x4){0.f, 0.f, 0.f, 0.f};
  acc[1] = (f32x4){0.f, 0.f, 0.f, 0.f};
#pragma unroll
  for (int kc = 0; kc < 4; kc++) {
    const f16x8 bf = *(const f16x8*)&XT[(nt * 16 + lr) * 136 + kc * 32 + quad * 8];
    acc[0] = __builtin_amdgcn_mfma_f32_16x16x32_f16(aW[0][kc], bf, acc[0], 0, 0, 0);
    acc[1] = __builtin_amdgcn_mfma_f32_16x16x32_f16(aW[1][kc], bf, acc[1], 0, 0, 0);
  }
#pragma unroll
  for (int t = 0; t < 2; t++) {
#pragma unroll
    for (int r = 0; r < 4; r++) {
      const int o = ob[t] + quad * 4 + r;
      const float val = acc[t][r] + (BIAS ? bias[o] : 0.f);
      Y[(size_t)(b * C + o) * N + n0 + nt * 16 + lr] = val;
      if (STAT) {
        float s = val, q = val * val;
        s += __shfl_xor(s, 1, 64); q += __shfl_xor(q, 1, 64);
        s += __shfl_xor(s, 2, 64); q += __shfl_xor(q, 2, 64);
        s += __shfl_xor(s, 4, 64); q += __shfl_xor(q, 4, 64);
        s += __shfl_xor(s, 8, 64); q += __shfl_xor(q, 8, 64);
        if (lr == 0) { statP[nt][o - oh * 64] = s; statQ[nt][o - oh * 64] = q; }
      }
    }
  }
  if (STAT) {
    __syncthreads();
    if (tid < 64) {
      const int o = oh * 64 + tid;
      const float s = statP[0][tid] + statP[1][tid] + statP[2][tid] + statP[3][tid];
      const float q = statQ[0][tid] + statQ[1][tid] + statQ[2][tid] + statQ[3][tid];
      const int part = blockIdx.x * 4 + b;
      bnpart[o * 512 + part] = s;
      bnpart[o * 512 + 256 + part] = q;
    }
  }
}

// ---------------------------------------------------------------------------
// Fused XV + QT projection via MFMA.  Outputs:
//  - QT  [b][n][32]      (original n space; k_pv A-operand for all m columns)
//  - QTc [b][j][32]      (compacted: only valid n, j = psum[n]; pads zero)
//  - XVc [b][c][j]       (compacted XV, f16, N-stride rows; pads zero)
//  - xvp [(b*C+o)][128]  per-block partial sums of XV over INVALID n (f32)
// grid (N/32, B), block 256.
// ---------------------------------------------------------------------------
__global__ __launch_bounds__(256) void k_qv(const _Float16* __restrict__ WFv,
                                            const _Float16* __restrict__ WFqk,
                                            const float* __restrict__ X,
                                            const float* __restrict__ bv,
                                            const int* __restrict__ mask,
                                            const int* __restrict__ psum,
                                            _Float16* __restrict__ XVc,
                                            _Float16* __restrict__ QT,
                                            _Float16* __restrict__ QTc,
                                            float* __restrict__ xvp) {
  __shared__ _Float16 XT[32 * 136];
  __shared__ float SP[2][128];
  const int tid = threadIdx.x;
  const int n0 = blockIdx.x * 32, b = blockIdx.y;
  const float* Xb = X + (size_t)(b * C) * N + n0;
#pragma unroll
  for (int i = 0; i < 4; i++) {              // 1024 float4: c=idx>>3, q=idx&7
    const int idx = tid + i * 256;
    const int c = idx >> 3, q = idx & 7;
    const float4 v = *(const float4*)&Xb[(size_t)c * N + q * 4];
    XT[(q * 4 + 0) * 136 + c] = (_Float16)v.x;
    XT[(q * 4 + 1) * 136 + c] = (_Float16)v.y;
    XT[(q * 4 + 2) * 136 + c] = (_Float16)v.z;
    XT[(q * 4 + 3) * 136 + c] = (_Float16)v.w;
  }
  __syncthreads();
  const int w = tid >> 6, lane = tid & 63, quad = lane >> 4, lr = lane & 15;
  const int nt = w & 1, og = w >> 1;
  const int n = n0 + nt * 16 + lr;
  const int vld = mask[b * N + n] != 0;
  const int jc = psum[b * N + n];
  f32x4 acc[5];
  const _Float16* Aptr[5];
  int otl[5];
#pragma unroll
  for (int j = 0; j < 5; j++) {
    acc[j] = (f32x4){0.f, 0.f, 0.f, 0.f};
    const int ot = og + 2 * j;
    otl[j] = ot;
    Aptr[j] = (ot < 8) ? (WFv + (size_t)(ot * 16 + lr) * 128)
                       : (WFqk + (size_t)((ot - 8) * 16 + lr) * 128);
  }
#pragma unroll
  for (int kc = 0; kc < 4; kc++) {
    const f16x8 bf = *(const f16x8*)&XT[(nt * 16 + lr) * 136 + kc * 32 + quad * 8];
#pragma unroll
    for (int j = 0; j < 5; j++) {
      const f16x8 a = *(const f16x8*)&Aptr[j][kc * 32 + quad * 8];
      acc[j] = __builtin_amdgcn_mfma_f32_16x16x32_f16(a, bf, acc[j], 0, 0, 0);
    }
  }
#pragma unroll
  for (int j = 0; j < 5; j++) {
    const int ot = otl[j];
    if (ot < 8) {
      float v[4];
#pragma unroll
      for (int r = 0; r < 4; r++) v[r] = acc[j][r] + bv[ot * 16 + quad * 4 + r];
      if (vld) {
#pragma unroll
        for (int r = 0; r < 4; r++)
          XVc[(size_t)(b * C + ot * 16 + quad * 4 + r) * N + jc] = (_Float16)v[r];
      }
      float s[4];
#pragma unroll
      for (int r = 0; r < 4; r++) s[r] = vld ? 0.f : v[r];
#pragma unroll
      for (int o = 1; o <= 8; o <<= 1) {
#pragma unroll
        for (int r = 0; r < 4; r++) s[r] += __shfl_xor(s[r], o, 64);
      }
      if (lr == 0) {
#pragma unroll
        for (int r = 0; r < 4; r++) SP[nt][ot * 16 + quad * 4 + r] = s[r];
      }
    } else {
      f16x4 qv;
#pragma unroll
      for (int r = 0; r < 4; r++) qv[r] = (_Float16)acc[j][r];
      const int qo = (ot - 8) * 16 + quad * 4;
      *(f16x4*)&QT[((size_t)b * N + n) * 32 + qo] = qv;
      if (vld) *(f16x4*)&QTc[((size_t)b * N + jc) * 32 + qo] = qv;
    }
  }
  __syncthreads();
  if (tid < 128)
    xvp[(size_t)(b * C + tid) * 128 + blockIdx.x] = SP[0][tid] + SP[1][tid];
}

// ---------------------------------------------------------------------------
// Row stats over COMPACTED space, single-pass online softmax.
// R13: 16 rows/block (512 active blocks -> 2 blocks/CU), pad-bias computed
// arithmetically (mrow<Nv) -- no 16KB mb[] LDS.  Block bx==256 instead
// reduces xvp -> xvi (folds the old k_xvr kernel in).
// rowst[b*N+row] = (rowmax, 1/rowsum).  grid (257, B), block 512.
// ---------------------------------------------------------------------------
__global__ __launch_bounds__(512) void k_sm(const _Float16* __restrict__ QTc,
                                            const int* __restrict__ nvb,
                                            const float* __restrict__ xvp,
                                            float* __restrict__ xvi,
                                            float2* __restrict__ rowst) {
  const int b = blockIdx.y, tid = threadIdx.x;
  if (blockIdx.x == 256) {                   // xvi reduction block
    __shared__ float xr[128][4];
    const int c = tid >> 2, q = tid & 3;
    const float* src = xvp + (size_t)(b * C + c) * 128 + q * 32;
    float v = 0.f;
#pragma unroll
    for (int i = 0; i < 32; i++) v += src[i];
    xr[c][q] = v;
    __syncthreads();
    if (tid < 128) xvi[b * C + tid] = xr[tid][0] + xr[tid][1] + xr[tid][2] + xr[tid][3];
    return;
  }
  const int Nv = nvb[b];
  const int NvpB = (Nv + 63) & ~63;
  const int n0 = blockIdx.x * 16;
  if (n0 >= NvpB) return;
  __shared__ float redM[8][16], redS[8][16];
  const _Float16* Qb = QTc + (size_t)b * N * 32;
  const int w = tid >> 6, lane = tid & 63, quad = lane >> 4, lr = lane & 15;
  const f16x8 aF = *(const f16x8*)&Qb[(size_t)(n0 + lr) * 32 + quad * 8];
  float mx[4] = {-3e38f, -3e38f, -3e38f, -3e38f};
  float s[4] = {0.f, 0.f, 0.f, 0.f};
  for (int ms = 0; ms < NvpB; ms += 128) {   // 8 waves x 16 m-cols per iter
    const int mrow = ms + w * 16 + lr;
    const f16x8 bF = *(const f16x8*)&Qb[(size_t)mrow * 32 + quad * 8];
    f32x4 d = (f32x4){0.f, 0.f, 0.f, 0.f};
    d = __builtin_amdgcn_mfma_f32_16x16x32_f16(aF, bF, d, 0, 0, 0);
    const float bias = (mrow < Nv) ? 0.0f : -1e30f;
#pragma unroll
    for (int r = 0; r < 4; r++) {
      const float dv = d[r] + bias;
      if (dv > mx[r]) {                      // rare after warm-up (defer-max)
        s[r] *= __expf(mx[r] - dv);
        mx[r] = dv;
      }
      s[r] += __expf(dv - mx[r]);
    }
  }
  // merge (mx,s) across the 16 lr lanes (butterfly log-sum-exp)
#pragma unroll
  for (int r = 0; r < 4; r++) {
#pragma unroll
    for (int o = 1; o <= 8; o <<= 1) {
      const float mo = __shfl_xor(mx[r], o, 64);
      const float so = __shfl_xor(s[r], o, 64);
      const float mn = fmaxf(mx[r], mo);
      s[r] = s[r] * __expf(mx[r] - mn) + so * __expf(mo - mn);
      mx[r] = mn;
    }
  }
  if (lr == 0)
#pragma unroll
    for (int r = 0; r < 4; r++) {
      redM[w][quad * 4 + r] = mx[r];
      redS[w][quad * 4 + r] = s[r];
    }
  __syncthreads();
  if (tid < 16) {
    float M = redM[0][tid];
#pragma unroll
    for (int k = 1; k < 8; k++) M = fmaxf(M, redM[k][tid]);
    float tot = 0.f;
#pragma unroll
    for (int k = 0; k < 8; k++) tot += redS[k][tid] * __expf(redM[k][tid] - M);
    const int row = n0 + tid;
    const bool valid = row < Nv;
    float2 rv;
    rv.x = valid ? M : 1e30f;
    rv.y = valid ? (1.0f / tot) : 0.0f;
    rowst[b * N + row] = rv;
  }
}

// ---------------------------------------------------------------------------
// Fused Gram->exp->PV, R13: m in ORIGINAL space (coalesced epilogue, vmb bias
// makes invalid-m columns produce acc=0/colS=0 so the k_fin formula is
// uniform) + SPLIT-K over compacted n (2 parts -> 1024 blocks, 3/CU, the
// latency-bound loop gets 1.5x TLP and ~half the steps per block).
// XVs LDS double-buffer retained (R2 proved direct-global A regresses).
// Partials: accbuf [blk][128c x 32m] f32, csbuf [blk][32m].
// grid (128, 2, B), block 512.
// ---------------------------------------------------------------------------
__global__ __launch_bounds__(512, 4) void k_pv(const _Float16* __restrict__ QT,
                                               const _Float16* __restrict__ QTc,
                                               const _Float16* __restrict__ XVc,
                                               const int* __restrict__ mask,
                                               const float2* __restrict__ rowst,
                                               const int* __restrict__ nvb,
                                               float* __restrict__ accbuf,
                                               float* __restrict__ csbuf) {
  __shared__ _Float16 XVs[2][128 * 72];
  __shared__ _Float16 Ps[2][32 * 72];
  __shared__ float colPart[4][32];
  const int tid = threadIdx.x;
  const int m0 = blockIdx.x * 32, part = blockIdx.y, b = blockIdx.z;
  const int Nv = nvb[b];
  const int ns = ((Nv + 63) & ~63) >> 6;
  const int half = ns >> 1;
  const int kb = part ? half : 0;
  const int ke = part ? ns : half;
  const _Float16* Qa = QT + (size_t)b * N * 32;
  const _Float16* Qc = QTc + (size_t)b * N * 32;
  const _Float16* XVb = XVc + (size_t)(b * C) * N;
  const float2* rsB = rowst + (size_t)b * N;
  const int w = tid >> 6, lane = tid & 63, quad = lane >> 4, lr = lane & 15;
  const int msub = w & 1, nsub = w >> 1;
  const f16x8 aG = *(const f16x8*)&Qa[(size_t)(m0 + msub * 16 + lr) * 32 + quad * 8];
  float vmb[4];
#pragma unroll
  for (int r = 0; r < 4; r++)
    vmb[r] = (mask[b * N + m0 + msub * 16 + quad * 4 + r] != 0) ? 0.0f : -1e30f;
  const int sc0 = tid >> 3, sh0 = tid & 7;   // XV staging rows (2 vec/thread)
  const int sc1 = sc0 + 64;
  f32x4 acc[2];
  acc[0] = (f32x4){0.f, 0.f, 0.f, 0.f};
  acc[1] = (f32x4){0.f, 0.f, 0.f, 0.f};
  float cs[4] = {0.f, 0.f, 0.f, 0.f};

  auto produce = [&](int k0, int bf) {
    const int nn = k0 + nsub * 16 + lr;
    const f16x8 bG = *(const f16x8*)&Qc[(size_t)nn * 32 + quad * 8];
    const f16x8 xv0 = *(const f16x8*)&XVb[(size_t)sc0 * N + k0 + sh0 * 8];
    const f16x8 xv1 = *(const f16x8*)&XVb[(size_t)sc1 * N + k0 + sh0 * 8];
    const float2 rr = rsB[nn];
    f32x4 e = (f32x4){0.f, 0.f, 0.f, 0.f};
    e = __builtin_amdgcn_mfma_f32_16x16x32_f16(aG, bG, e, 0, 0, 0);
    *(f16x8*)&XVs[bf][sc0 * 72 + sh0 * 8] = xv0;
    *(f16x8*)&XVs[bf][sc1 * 72 + sh0 * 8] = xv1;
#pragma unroll
    for (int r = 0; r < 4; r++) {
      const float p = __expf(e[r] - rr.x + vmb[r]) * rr.y;  // pad rows: ri=0 -> 0
      cs[r] += p;
      Ps[bf][(msub * 16 + quad * 4 + r) * 72 + nsub * 16 + lr] = (_Float16)p;
    }
  };
  auto consume = [&](int bf) {
    const int c0 = w * 16;
    const f16x8 a0 = *(const f16x8*)&XVs[bf][(c0 + lr) * 72 + quad * 8];
    const f16x8 a1 = *(const f16x8*)&XVs[bf][(c0 + lr) * 72 + 32 + quad * 8];
    const f16x8 b00 = *(const f16x8*)&Ps[bf][lr * 72 + quad * 8];
    const f16x8 b01 = *(const f16x8*)&Ps[bf][lr * 72 + 32 + quad * 8];
    const f16x8 b10 = *(const f16x8*)&Ps[bf][(16 + lr) * 72 + quad * 8];
    const f16x8 b11 = *(const f16x8*)&Ps[bf][(16 + lr) * 72 + 32 + quad * 8];
    acc[0] = __builtin_amdgcn_mfma_f32_16x16x32_f16(a0, b00, acc[0], 0, 0, 0);
    acc[0] = __builtin_amdgcn_mfma_f32_16x16x32_f16(a1, b01, acc[0], 0, 0, 0);
    acc[1] = __builtin_amdgcn_mfma_f32_16x16x32_f16(a0, b10, acc[1], 0, 0, 0);
    acc[1] = __builtin_amdgcn_mfma_f32_16x16x32_f16(a1, b11, acc[1], 0, 0, 0);
  };

  if (kb < ke) produce(kb * 64, 0);
  __syncthreads();
  for (int it = kb; it < ke; it += 2) {
    if (it + 1 < ke) produce((it + 1) * 64, 1);
    consume(0);
    __syncthreads();
    if (it + 1 < ke) {
      if (it + 2 < ke) produce((it + 2) * 64, 0);
      consume(1);
      __syncthreads();
    }
  }
#pragma unroll
  for (int r = 0; r < 4; r++) {
    float v = cs[r];
    v += __shfl_xor(v, 1, 64);
    v += __shfl_xor(v, 2, 64);
    v += __shfl_xor(v, 4, 64);
    v += __shfl_xor(v, 8, 64);
    cs[r] = v;
  }
  if (lr == 0)
#pragma unroll
    for (int r = 0; r < 4; r++) colPart[nsub][msub * 16 + quad * 4 + r] = cs[r];
  __syncthreads();
  const size_t blk = (size_t)(b * 128 + blockIdx.x) * 2 + part;
  if (tid < 32)
    csbuf[blk * 32 + tid] =
        colPart[0][tid] + colPart[1][tid] + colPart[2][tid] + colPart[3][tid];
  const size_t ab = blk * 4096;
  const int cg = w * 16 + quad * 4;
#pragma unroll
  for (int r = 0; r < 4; r++) {
    accbuf[ab + (size_t)(cg + r) * 32 + lr] = acc[0][r];
    accbuf[ab + (size_t)(cg + r) * 32 + 16 + lr] = acc[1][r];
  }
}

// ---------------------------------------------------------------------------
// Final combine (fully coalesced, m original space): reduce the 2 split-K
// partials, add the invalid-row rank-1 term, renormalize, write Td.
// For invalid m the same formula is exact (acc=0, colS=0).
// grid (128, B), 256 thr, float4 throughout.
// ---------------------------------------------------------------------------
__global__ __launch_bounds__(256) void k_fin(const float* __restrict__ accbuf,
                                             const float* __restrict__ csbuf,
                                             const int* __restrict__ nvb,
                                             const float* __restrict__ xvi,
                                             const float* __restrict__ H,
                                             float* __restrict__ Td) {
  const int b = blockIdx.y, tid = threadIdx.x, bx = blockIdx.x;
  const int Nv = nvb[b];
  constexpr float qq = 0.000244140625f;      // 1/4096
  __shared__ float rdivS[32];
  __shared__ float xviS[128];
  const float ninvq = (float)(N - Nv) * qq;
  const size_t blk2 = (size_t)(b * 128 + bx) * 2;
  if (tid < 32) {
    const float csv = csbuf[blk2 * 32 + tid] + csbuf[blk2 * 32 + 32 + tid];
    rdivS[tid] = 1.0f / (1e-9f + csv + ninvq);
  }
  if (tid >= 128) xviS[tid - 128] = xvi[b * C + tid - 128];
  __syncthreads();
  const size_t ab = blk2 * 4096;
  const int m0 = bx * 32;
#pragma unroll
  for (int k = 0; k < 4; k++) {
    const int i4 = tid + k * 256;            // 1024 float4 = 128c x 8 m-quads
    const int c = i4 >> 3, mq = (i4 & 7) * 4;
    const float4 a0 = *(const float4*)&accbuf[ab + c * 32 + mq];
    const float4 a1 = *(const float4*)&accbuf[ab + 4096 + c * 32 + mq];
    const float xadd = xviS[c] * qq;
    const size_t gi = (size_t)(b * C + c) * N + m0 + mq;
    const float4 h = *(const float4*)&H[gi];
    float4 r;
    r.x = h.x - (a0.x + a1.x + xadd) * rdivS[mq + 0];
    r.y = h.y - (a0.y + a1.y + xadd) * rdivS[mq + 1];
    r.z = h.z - (a0.z + a1.z + xadd) * rdivS[mq + 2];
    r.w = h.w - (a0.w + a1.w + xadd) * rdivS[mq + 3];
    *(float4*)&Td[gi] = r;
  }
}

// ---------------------------------------------------------------------------
// Apply BN+ReLU (+residual, +write output slice). grid 2048, 256 thr, float4.
// ---------------------------------------------------------------------------
template<bool RES>
__global__ __launch_bounds__(256) void k_apply(const float* __restrict__ T2,
                                               const float* __restrict__ bnpart,
                                               const float* __restrict__ gamma,
                                               const float* __restrict__ beta,
                                               float* __restrict__ H,
                                               float* __restrict__ Out) {
  __shared__ float rs[4], rq[4], bc[2];
  const int tid = threadIdx.x;
  const int f = (blockIdx.x * 256 + tid) * 4;
  const int c = (blockIdx.x >> 2) & 127;
  float s = bnpart[c * 512 + tid];
  float q = bnpart[c * 512 + 256 + tid];
#pragma unroll
  for (int o = 1; o <= 32; o <<= 1) { s += __shfl_xor(s, o, 64); q += __shfl_xor(q, o, 64); }
  if ((tid & 63) == 0) { rs[tid >> 6] = s; rq[tid >> 6] = q; }
  __syncthreads();
  if (tid == 0) {
    const float st = rs[0] + rs[1] + rs[2] + rs[3];
    const float qt = rq[0] + rq[1] + rq[2] + rq[3];
    const float inv = 1.0f / (B * N);
    const float mean = st * inv;
    const float var = qt * inv - mean * mean;   // biased, like torch BN
    const float sc = gamma[c] * rsqrtf(var + 1e-5f);
    bc[0] = sc;
    bc[1] = beta[c] - mean * sc;
  }
  __syncthreads();
  const float sc = bc[0], sh = bc[1];
  const float4 t = *(const float4*)&T2[f];
  float4 r;
  r.x = fmaxf(t.x * sc + sh, 0.f);
  r.y = fmaxf(t.y * sc + sh, 0.f);
  r.z = fmaxf(t.z * sc + sh, 0.f);
  r.w = fmaxf(t.w * sc + sh, 0.f);
  if (RES) {
    const float4 h = *(const float4*)&H[f];
    r.x += h.x; r.y += h.y; r.z += h.z; r.w += h.w;
    *(float4*)&H[f] = r;
    const int b = f >> 19;                // f / (C*N)
    const int rem = f & (C * N - 1);      // c*N + n
    *(float4*)&Out[(size_t)b * (4 * C * N) + rem] = r;
  } else {
    *(float4*)&H[f] = r;
  }
}

// ---------------------------------------------------------------------------
extern "C" void kernel_launch(void* const* d_in, const int* in_sizes, int n_in,
                              void* d_out, int out_size, void* d_ws, size_t ws_size,
                              hipStream_t stream) {
  const float* x    = (const float*)d_in[0];
  const int*   mask = (const int*)  d_in[1];
  const float* w1   = (const float*)d_in[2];
  const float* g1   = (const float*)d_in[3];
  const float* b1   = (const float*)d_in[4];
  const float* w2   = (const float*)d_in[5];
  const float* g2   = (const float*)d_in[6];
  const float* b2   = (const float*)d_in[7];
  const float* wqk  = (const float*)d_in[8];
  const float* wv   = (const float*)d_in[9];
  const float* bv   = (const float*)d_in[10];
  const float* wt   = (const float*)d_in[11];
  const float* bt   = (const float*)d_in[12];
  const float* sg   = (const float*)d_in[13];
  const float* sb   = (const float*)d_in[14];
  float* out = (float*)d_out;

  char* p = (char*)d_ws;
  auto alloc = [&](size_t bytes) { char* r = p; p += (bytes + 255) & ~(size_t)255; return r; };
  float*    H      = (float*)   alloc((size_t)B * C * N * 4);
  float*    T2     = (float*)   alloc((size_t)B * C * N * 4);
  float*    Td     = (float*)   alloc((size_t)B * C * N * 4);
  _Float16* QT     = (_Float16*)alloc((size_t)B * N * 32 * 2);
  _Float16* QTc    = (_Float16*)alloc((size_t)B * N * 32 * 2);   // contiguous with
  _Float16* XVc    = (_Float16*)alloc((size_t)B * C * N * 2);    // XVc: one memset
  float2*   rowst  = (float2*)  alloc((size_t)B * N * 8);
  float*    bnpart = (float*)   alloc((size_t)C * 512 * 4);
  int*      psum   = (int*)     alloc((size_t)B * N * 4);
  int*      nvb    = (int*)     alloc(256);
  float*    xvp    = (float*)   alloc((size_t)B * C * 128 * 4);
  float*    xvi    = (float*)   alloc((size_t)B * C * 4);
  float*    accbuf = (float*)   alloc((size_t)B * 128 * 2 * 4096 * 4);
  float*    csbuf  = (float*)   alloc((size_t)B * 128 * 2 * 32 * 4);
  _Float16* WF     = (_Float16*)alloc((size_t)180224 * 2);
  (void)ws_size;
  _Float16* wf1  = WF;
  _Float16* wf2  = WF + 16384;
  _Float16* wfv  = WF + 32768;
  _Float16* wft  = WF + 98304;
  _Float16* wfqk = WF + 163840;

  // ---- one-shot setup: weight convert, mask compaction, pad zeroing ----
  k_wcvt<<<176, 256, 0, stream>>>(w1, w2, wv, wt, wqk, WF);
  k_mask<<<B, 1024, 0, stream>>>(mask, psum, nvb);
  hipMemsetAsync(QTc, 0, (size_t)B * N * 32 * 2 + (size_t)B * C * N * 2, stream);

  // ---- stem: two conv1d(+BN+ReLU), MFMA, BN partials fused ----
  k_gwm<false, true><<<dim3(64, 2, B), 512, 0, stream>>>(wf1, x, nullptr, T2, bnpart);
  k_apply<false><<<2048, 256, 0, stream>>>(T2, bnpart, g1, b1, H, nullptr);
  k_gwm<false, true><<<dim3(64, 2, B), 512, 0, stream>>>(wf2, H, nullptr, T2, bnpart);
  k_apply<false><<<2048, 256, 0, stream>>>(T2, bnpart, g2, b2, H, nullptr);

  // ---- 4 chained offset-attention layers (flash-style, split-K PV) ----
  for (int L = 0; L < 4; L++) {
    k_qv<<<dim3(128, B), 256, 0, stream>>>(wfv + (size_t)L * 16384, wfqk + (size_t)L * 4096,
                                           H, bv + L * C, mask, psum, XVc, QT, QTc, xvp);
    k_sm<<<dim3(257, B), 512, 0, stream>>>(QTc, nvb, xvp, xvi, rowst);
    k_pv<<<dim3(128, 2, B), 512, 0, stream>>>(QT, QTc, XVc, mask, rowst, nvb, accbuf, csbuf);
    k_fin<<<dim3(128, B), 256, 0, stream>>>(accbuf, csbuf, nvb, xvi, H, Td);
    k_gwm<true, true><<<dim3(64, 2, B), 512, 0, stream>>>(wft + (size_t)L * 16384, Td, bt + L * C, T2, bnpart);
    k_apply<true><<<2048, 256, 0, stream>>>(T2, bnpart, sg + L * C, sb + L * C, H, out + (size_t)L * C * N);
  }
}

// Round 5
// 474.015 us; speedup vs baseline: 1.0377x; 1.0377x over previous
//
#include <hip/hip_runtime.h>
#include <hip/hip_fp16.h>

constexpr int C = 128;
constexpr int N = 4096;
constexpr int B = 4;

typedef _Float16 f16x8 __attribute__((ext_vector_type(8)));
typedef _Float16 f16x4 __attribute__((ext_vector_type(4)));
typedef float    f32x4 __attribute__((ext_vector_type(4)));

// ---------------------------------------------------------------------------
// One-shot weight convert fp32 -> f16 into workspace, concatenated:
// [w1(16K) | w2(16K) | wv(64K) | wt(64K) | wqk(16K)] elements.
// grid 176, 256 thr; each thread converts one float4.
// ---------------------------------------------------------------------------
__global__ __launch_bounds__(256) void k_wcvt(const float* __restrict__ w1,
                                              const float* __restrict__ w2,
                                              const float* __restrict__ wv,
                                              const float* __restrict__ wt,
                                              const float* __restrict__ wqk,
                                              _Float16* __restrict__ WF) {
  const int g = blockIdx.x * 256 + threadIdx.x;   // float4 index
  const float* src; int off;
  if (g < 4096)       { src = w1;  off = g; }
  else if (g < 8192)  { src = w2;  off = g - 4096; }
  else if (g < 24576) { src = wv;  off = g - 8192; }
  else if (g < 40960) { src = wt;  off = g - 24576; }
  else                { src = wqk; off = g - 40960; }
  const float4 v = ((const float4*)src)[off];
  f16x4 h = {(_Float16)v.x, (_Float16)v.y, (_Float16)v.z, (_Float16)v.w};
  *(f16x4*)&WF[(size_t)g * 4] = h;
}

// ---------------------------------------------------------------------------
// Mask compaction: exclusive prefix sum of (mask!=0) per batch + valid count.
// grid B, 1024 thr (4 elements/thread).
// ---------------------------------------------------------------------------
__global__ __launch_bounds__(1024) void k_mask(const int* __restrict__ mask,
                                               int* __restrict__ psum,
                                               int* __restrict__ nvb) {
  const int b = blockIdx.x, tid = threadIdx.x;
  __shared__ int wsum[16];
  const int4 mv = *(const int4*)&mask[b * N + tid * 4];
  const int m0 = (mv.x != 0), m1 = (mv.y != 0), m2 = (mv.z != 0), m3 = (mv.w != 0);
  const int s0 = m0, s1 = s0 + m1, s2 = s1 + m2, s3 = s2 + m3;
  const int lane = tid & 63, w = tid >> 6;
  int sc = s3;
#pragma unroll
  for (int o = 1; o < 64; o <<= 1) {
    const int v = __shfl_up(sc, o, 64);
    if (lane >= o) sc += v;
  }
  if (lane == 63) wsum[w] = sc;
  __syncthreads();
  if (tid < 16) {
    int v = wsum[tid];
#pragma unroll
    for (int o = 1; o < 16; o <<= 1) {
      const int u = __shfl_up(v, o, 64);
      if (tid >= o) v += u;
    }
    wsum[tid] = v;
  }
  __syncthreads();
  const int excl = ((w > 0) ? wsum[w - 1] : 0) + sc - s3;
  int4 pv;
  pv.x = excl; pv.y = excl + s0; pv.z = excl + s1; pv.w = excl + s2;
  *(int4*)&psum[b * N + tid * 4] = pv;
  if (tid == 0) nvb[b] = wsum[15];
}

// ---------------------------------------------------------------------------
// MFMA projection GEMM. Y[b,o,n] = sum_c W[o,c]*X[b,c,n] (+bias), fp32 out.
// grid (N/64, 2, B), block 512.
// ---------------------------------------------------------------------------
template<bool BIAS, bool STAT>
__global__ __launch_bounds__(512) void k_gwm(const _Float16* __restrict__ WF,
                                             const float* __restrict__ X,
                                             const float* __restrict__ bias,
                                             float* __restrict__ Y,
                                             float* __restrict__ bnpart) {
  __shared__ _Float16 XT[64 * 136];          // [n][c], stride 136 (16B-aligned rows)
  __shared__ float statP[4][64], statQ[4][64];
  const int tid = threadIdx.x;
  const int n0 = blockIdx.x * 64, oh = blockIdx.y, b = blockIdx.z;
  const float* Xb = X + (size_t)(b * C) * N + n0;
#pragma unroll
  for (int i = 0; i < 4; i++) {              // 2048 float4: c=idx>>4, q=idx&15
    const int idx = tid + i * 512;
    const int c = idx >> 4, q = idx & 15;
    const float4 v = *(const float4*)&Xb[(size_t)c * N + q * 4];
    XT[(q * 4 + 0) * 136 + c] = (_Float16)v.x;
    XT[(q * 4 + 1) * 136 + c] = (_Float16)v.y;
    XT[(q * 4 + 2) * 136 + c] = (_Float16)v.z;
    XT[(q * 4 + 3) * 136 + c] = (_Float16)v.w;
  }
  __syncthreads();
  const int w = tid >> 6, lane = tid & 63, quad = lane >> 4, lr = lane & 15;
  const int nt = w & 3, og = w >> 2;
  const int ob[2] = {oh * 64 + og * 16, oh * 64 + (og + 2) * 16};
  f16x8 aW[2][4];
#pragma unroll
  for (int t = 0; t < 2; t++)
#pragma unroll
    for (int kc = 0; kc < 4; kc++)
      aW[t][kc] = *(const f16x8*)&WF[(size_t)(ob[t] + lr) * 128 + kc * 32 + quad * 8];
  f32x4 acc[2];
  acc[0] = (f32x4){0.f, 0.f, 0.f, 0.f};
  acc[1] = (f32x4){0.f, 0.f, 0.f, 0.f};
#pragma unroll
  for (int kc = 0; kc < 4; kc++) {
    const f16x8 bf = *(const f16x8*)&XT[(nt * 16 + lr) * 136 + kc * 32 + quad * 8];
    acc[0] = __builtin_amdgcn_mfma_f32_16x16x32_f16(aW[0][kc], bf, acc[0], 0, 0, 0);
    acc[1] = __builtin_amdgcn_mfma_f32_16x16x32_f16(aW[1][kc], bf, acc[1], 0, 0, 0);
  }
#pragma unroll
  for (int t = 0; t < 2; t++) {
#pragma unroll
    for (int r = 0; r < 4; r++) {
      const int o = ob[t] + quad * 4 + r;
      const float val = acc[t][r] + (BIAS ? bias[o] : 0.f);
      Y[(size_t)(b * C + o) * N + n0 + nt * 16 + lr] = val;
      if (STAT) {
        float s = val, q = val * val;
        s += __shfl_xor(s, 1, 64); q += __shfl_xor(q, 1, 64);
        s += __shfl_xor(s, 2, 64); q += __shfl_xor(q, 2, 64);
        s += __shfl_xor(s, 4, 64); q += __shfl_xor(q, 4, 64);
        s += __shfl_xor(s, 8, 64); q += __shfl_xor(q, 8, 64);
        if (lr == 0) { statP[nt][o - oh * 64] = s; statQ[nt][o - oh * 64] = q; }
      }
    }
  }
  if (STAT) {
    __syncthreads();
    if (tid < 64) {
      const int o = oh * 64 + tid;
      const float s = statP[0][tid] + statP[1][tid] + statP[2][tid] + statP[3][tid];
      const float q = statQ[0][tid] + statQ[1][tid] + statQ[2][tid] + statQ[3][tid];
      const int part = blockIdx.x * 4 + b;
      bnpart[o * 512 + part] = s;
      bnpart[o * 512 + 256 + part] = q;
    }
  }
}

// ---------------------------------------------------------------------------
// Fused XV + QT projection via MFMA.  Outputs:
//  - QT  [b][n][32]      (original n space; k_pv A-operand for all m columns)
//  - QTc [b][j][32]      (compacted: only valid n, j = psum[n]; pads zero)
//  - XVc [b][c][j]       (compacted XV, f16, N-stride rows; pads zero)
//  - xvp [(b*C+o)][128]  per-block partial sums of XV over INVALID n (f32)
// grid (N/32, B), block 256.
// ---------------------------------------------------------------------------
__global__ __launch_bounds__(256) void k_qv(const _Float16* __restrict__ WFv,
                                            const _Float16* __restrict__ WFqk,
                                            const float* __restrict__ X,
                                            const float* __restrict__ bv,
                                            const int* __restrict__ mask,
                                            const int* __restrict__ psum,
                                            _Float16* __restrict__ XVc,
                                            _Float16* __restrict__ QT,
                                            _Float16* __restrict__ QTc,
                                            float* __restrict__ xvp) {
  __shared__ _Float16 XT[32 * 136];
  __shared__ float SP[2][128];
  const int tid = threadIdx.x;
  const int n0 = blockIdx.x * 32, b = blockIdx.y;
  const float* Xb = X + (size_t)(b * C) * N + n0;
#pragma unroll
  for (int i = 0; i < 4; i++) {              // 1024 float4: c=idx>>3, q=idx&7
    const int idx = tid + i * 256;
    const int c = idx >> 3, q = idx & 7;
    const float4 v = *(const float4*)&Xb[(size_t)c * N + q * 4];
    XT[(q * 4 + 0) * 136 + c] = (_Float16)v.x;
    XT[(q * 4 + 1) * 136 + c] = (_Float16)v.y;
    XT[(q * 4 + 2) * 136 + c] = (_Float16)v.z;
    XT[(q * 4 + 3) * 136 + c] = (_Float16)v.w;
  }
  __syncthreads();
  const int w = tid >> 6, lane = tid & 63, quad = lane >> 4, lr = lane & 15;
  const int nt = w & 1, og = w >> 1;
  const int n = n0 + nt * 16 + lr;
  const int vld = mask[b * N + n] != 0;
  const int jc = psum[b * N + n];
  f32x4 acc[5];
  const _Float16* Aptr[5];
  int otl[5];
#pragma unroll
  for (int j = 0; j < 5; j++) {
    acc[j] = (f32x4){0.f, 0.f, 0.f, 0.f};
    const int ot = og + 2 * j;
    otl[j] = ot;
    Aptr[j] = (ot < 8) ? (WFv + (size_t)(ot * 16 + lr) * 128)
                       : (WFqk + (size_t)((ot - 8) * 16 + lr) * 128);
  }
#pragma unroll
  for (int kc = 0; kc < 4; kc++) {
    const f16x8 bf = *(const f16x8*)&XT[(nt * 16 + lr) * 136 + kc * 32 + quad * 8];
#pragma unroll
    for (int j = 0; j < 5; j++) {
      const f16x8 a = *(const f16x8*)&Aptr[j][kc * 32 + quad * 8];
      acc[j] = __builtin_amdgcn_mfma_f32_16x16x32_f16(a, bf, acc[j], 0, 0, 0);
    }
  }
#pragma unroll
  for (int j = 0; j < 5; j++) {
    const int ot = otl[j];
    if (ot < 8) {
      float v[4];
#pragma unroll
      for (int r = 0; r < 4; r++) v[r] = acc[j][r] + bv[ot * 16 + quad * 4 + r];
      if (vld) {
#pragma unroll
        for (int r = 0; r < 4; r++)
          XVc[(size_t)(b * C + ot * 16 + quad * 4 + r) * N + jc] = (_Float16)v[r];
      }
      float s[4];
#pragma unroll
      for (int r = 0; r < 4; r++) s[r] = vld ? 0.f : v[r];
#pragma unroll
      for (int o = 1; o <= 8; o <<= 1) {
#pragma unroll
        for (int r = 0; r < 4; r++) s[r] += __shfl_xor(s[r], o, 64);
      }
      if (lr == 0) {
#pragma unroll
        for (int r = 0; r < 4; r++) SP[nt][ot * 16 + quad * 4 + r] = s[r];
      }
    } else {
      f16x4 qv;
#pragma unroll
      for (int r = 0; r < 4; r++) qv[r] = (_Float16)acc[j][r];
      const int qo = (ot - 8) * 16 + quad * 4;
      *(f16x4*)&QT[((size_t)b * N + n) * 32 + qo] = qv;
      if (vld) *(f16x4*)&QTc[((size_t)b * N + jc) * 32 + qo] = qv;
    }
  }
  __syncthreads();
  if (tid < 128)
    xvp[(size_t)(b * C + tid) * 128 + blockIdx.x] = SP[0][tid] + SP[1][tid];
}

// ---------------------------------------------------------------------------
// Row stats over COMPACTED space, single-pass online softmax.
// 16 rows/block (~2x active blocks vs 64-row two-pass; half the Gram MFMA),
// pad-bias arithmetic (mrow<Nv) -- no mb[] LDS.  Block bx==256 instead
// reduces xvp -> xvi (folds the old k_xvr kernel in).
// rowst[b*N+row] = (rowmax, 1/rowsum).  grid (257, B), block 512.
// ---------------------------------------------------------------------------
__global__ __launch_bounds__(512) void k_sm(const _Float16* __restrict__ QTc,
                                            const int* __restrict__ nvb,
                                            const float* __restrict__ xvp,
                                            float* __restrict__ xvi,
                                            float2* __restrict__ rowst) {
  const int b = blockIdx.y, tid = threadIdx.x;
  if (blockIdx.x == 256) {                   // xvi reduction block
    __shared__ float xr[128][4];
    const int c = tid >> 2, q = tid & 3;
    const float* src = xvp + (size_t)(b * C + c) * 128 + q * 32;
    float v = 0.f;
#pragma unroll
    for (int i = 0; i < 32; i++) v += src[i];
    xr[c][q] = v;
    __syncthreads();
    if (tid < 128) xvi[b * C + tid] = xr[tid][0] + xr[tid][1] + xr[tid][2] + xr[tid][3];
    return;
  }
  const int Nv = nvb[b];
  const int NvpB = (Nv + 63) & ~63;
  const int n0 = blockIdx.x * 16;
  if (n0 >= NvpB) return;
  __shared__ float redM[8][16], redS[8][16];
  const _Float16* Qb = QTc + (size_t)b * N * 32;
  const int w = tid >> 6, lane = tid & 63, quad = lane >> 4, lr = lane & 15;
  const f16x8 aF = *(const f16x8*)&Qb[(size_t)(n0 + lr) * 32 + quad * 8];
  float mx[4] = {-3e38f, -3e38f, -3e38f, -3e38f};
  float s[4] = {0.f, 0.f, 0.f, 0.f};
  for (int ms = 0; ms < NvpB; ms += 128) {   // 8 waves x 16 m-cols per iter
    const int mrow = ms + w * 16 + lr;
    const f16x8 bF = *(const f16x8*)&Qb[(size_t)mrow * 32 + quad * 8];
    f32x4 d = (f32x4){0.f, 0.f, 0.f, 0.f};
    d = __builtin_amdgcn_mfma_f32_16x16x32_f16(aF, bF, d, 0, 0, 0);
    const float bias = (mrow < Nv) ? 0.0f : -1e30f;
#pragma unroll
    for (int r = 0; r < 4; r++) {
      const float dv = d[r] + bias;
      if (dv > mx[r]) {                      // rare after warm-up (defer-max)
        s[r] *= __expf(mx[r] - dv);
        mx[r] = dv;
      }
      s[r] += __expf(dv - mx[r]);
    }
  }
  // merge (mx,s) across the 16 lr lanes (butterfly log-sum-exp)
#pragma unroll
  for (int r = 0; r < 4; r++) {
#pragma unroll
    for (int o = 1; o <= 8; o <<= 1) {
      const float mo = __shfl_xor(mx[r], o, 64);
      const float so = __shfl_xor(s[r], o, 64);
      const float mn = fmaxf(mx[r], mo);
      s[r] = s[r] * __expf(mx[r] - mn) + so * __expf(mo - mn);
      mx[r] = mn;
    }
  }
  if (lr == 0)
#pragma unroll
    for (int r = 0; r < 4; r++) {
      redM[w][quad * 4 + r] = mx[r];
      redS[w][quad * 4 + r] = s[r];
    }
  __syncthreads();
  if (tid < 16) {
    float M = redM[0][tid];
#pragma unroll
    for (int k = 1; k < 8; k++) M = fmaxf(M, redM[k][tid]);
    float tot = 0.f;
#pragma unroll
    for (int k = 0; k < 8; k++) tot += redS[k][tid] * __expf(redM[k][tid] - M);
    const int row = n0 + tid;
    const bool valid = row < Nv;
    float2 rv;
    rv.x = valid ? M : 1e30f;
    rv.y = valid ? (1.0f / tot) : 0.0f;
    rowst[b * N + row] = rv;
  }
}

// ---------------------------------------------------------------------------
// Fused Gram->exp->PV: the R1-proven monolithic structure (456us baseline).
// COMPACTED n loop (valid rows only), m in ORIGINAL space (coalesced direct
// Td epilogue; vmb bias handles invalid m).  XVs/Ps LDS double-buffer,
// produce(k+1) overlaps consume(k), one barrier per 64-n step.
// Invalid-row uniform-attn contribution added analytically in the epilogue:
//   x_r = (acc + xvInvSum/4096) / (1e-9 + colS + ninv/4096)
// grid (N/32, B), block 512.
// ---------------------------------------------------------------------------
__global__ __launch_bounds__(512, 4) void k_pv(const _Float16* __restrict__ QT,
                                               const _Float16* __restrict__ QTc,
                                               const _Float16* __restrict__ XVc,
                                               const float* __restrict__ H,
                                               const int* __restrict__ mask,
                                               const float2* __restrict__ rowst,
                                               const int* __restrict__ nvb,
                                               const float* __restrict__ xvi,
                                               float* __restrict__ Td) {
  __shared__ _Float16 XVs[2][128 * 72];
  __shared__ _Float16 Ps[2][32 * 72];
  __shared__ float colPart[4][32];
  __shared__ float colS[32];
  const int tid = threadIdx.x;
  const int m0 = blockIdx.x * 32, b = blockIdx.y;
  const int Nv = nvb[b];
  const int ns = ((Nv + 63) & ~63) >> 6;
  const _Float16* Qa = QT + (size_t)b * N * 32;
  const _Float16* Qc = QTc + (size_t)b * N * 32;
  const _Float16* XVb = XVc + (size_t)(b * C) * N;
  const float2* rsB = rowst + (size_t)b * N;
  const int w = tid >> 6, lane = tid & 63, quad = lane >> 4, lr = lane & 15;
  const int msub = w & 1, nsub = w >> 1;
  const f16x8 aG = *(const f16x8*)&Qa[(size_t)(m0 + msub * 16 + lr) * 32 + quad * 8];
  float vmb[4];
#pragma unroll
  for (int r = 0; r < 4; r++)
    vmb[r] = (mask[b * N + m0 + msub * 16 + quad * 4 + r] != 0) ? 0.0f : -1e30f;
  const int sc0 = tid >> 3, sh0 = tid & 7;   // XV staging rows (2 vec/thread)
  const int sc1 = sc0 + 64;
  f32x4 acc[2];
  acc[0] = (f32x4){0.f, 0.f, 0.f, 0.f};
  acc[1] = (f32x4){0.f, 0.f, 0.f, 0.f};
  float cs[4] = {0.f, 0.f, 0.f, 0.f};

  auto produce = [&](int k0, int bf) {
    const int nn = k0 + nsub * 16 + lr;
    const f16x8 bG = *(const f16x8*)&Qc[(size_t)nn * 32 + quad * 8];
    const f16x8 xv0 = *(const f16x8*)&XVb[(size_t)sc0 * N + k0 + sh0 * 8];
    const f16x8 xv1 = *(const f16x8*)&XVb[(size_t)sc1 * N + k0 + sh0 * 8];
    const float2 rr = rsB[nn];
    f32x4 e = (f32x4){0.f, 0.f, 0.f, 0.f};
    e = __builtin_amdgcn_mfma_f32_16x16x32_f16(aG, bG, e, 0, 0, 0);
    *(f16x8*)&XVs[bf][sc0 * 72 + sh0 * 8] = xv0;
    *(f16x8*)&XVs[bf][sc1 * 72 + sh0 * 8] = xv1;
#pragma unroll
    for (int r = 0; r < 4; r++) {
      const float p = __expf(e[r] - rr.x + vmb[r]) * rr.y;  // pad rows: ri=0 -> 0
      cs[r] += p;
      Ps[bf][(msub * 16 + quad * 4 + r) * 72 + nsub * 16 + lr] = (_Float16)p;
    }
  };
  auto consume = [&](int bf) {
    const int c0 = w * 16;
    const f16x8 a0 = *(const f16x8*)&XVs[bf][(c0 + lr) * 72 + quad * 8];
    const f16x8 a1 = *(const f16x8*)&XVs[bf][(c0 + lr) * 72 + 32 + quad * 8];
    const f16x8 b00 = *(const f16x8*)&Ps[bf][lr * 72 + quad * 8];
    const f16x8 b01 = *(const f16x8*)&Ps[bf][lr * 72 + 32 + quad * 8];
    const f16x8 b10 = *(const f16x8*)&Ps[bf][(16 + lr) * 72 + quad * 8];
    const f16x8 b11 = *(const f16x8*)&Ps[bf][(16 + lr) * 72 + 32 + quad * 8];
    acc[0] = __builtin_amdgcn_mfma_f32_16x16x32_f16(a0, b00, acc[0], 0, 0, 0);
    acc[0] = __builtin_amdgcn_mfma_f32_16x16x32_f16(a1, b01, acc[0], 0, 0, 0);
    acc[1] = __builtin_amdgcn_mfma_f32_16x16x32_f16(a0, b10, acc[1], 0, 0, 0);
    acc[1] = __builtin_amdgcn_mfma_f32_16x16x32_f16(a1, b11, acc[1], 0, 0, 0);
  };

  if (ns > 0) produce(0, 0);
  __syncthreads();
  for (int it = 0; it < ns; it += 2) {
    if (it + 1 < ns) produce((it + 1) * 64, 1);
    consume(0);
    __syncthreads();
    if (it + 1 < ns) {
      if (it + 2 < ns) produce((it + 2) * 64, 0);
      consume(1);
      __syncthreads();
    }
  }
#pragma unroll
  for (int r = 0; r < 4; r++) {
    float v = cs[r];
    v += __shfl_xor(v, 1, 64);
    v += __shfl_xor(v, 2, 64);
    v += __shfl_xor(v, 4, 64);
    v += __shfl_xor(v, 8, 64);
    cs[r] = v;
  }
  if (lr == 0)
#pragma unroll
    for (int r = 0; r < 4; r++) colPart[nsub][msub * 16 + quad * 4 + r] = cs[r];
  __syncthreads();
  if (tid < 32)
    colS[tid] = colPart[0][tid] + colPart[1][tid] + colPart[2][tid] + colPart[3][tid];
  __syncthreads();
  const float ninvq = (float)(N - Nv) * 0.000244140625f;   // ninv/4096
  const float rdiv0 = 1.0f / (1e-9f + colS[lr] + ninvq);
  const float rdiv1 = 1.0f / (1e-9f + colS[16 + lr] + ninvq);
  const int cg = b * C + w * 16 + quad * 4;
#pragma unroll
  for (int r = 0; r < 4; r++) {
    const float xadd = xvi[cg + r] * 0.000244140625f;      // xvInvSum/4096
    const size_t gi0 = (size_t)(cg + r) * N + m0 + lr;
    Td[gi0] = H[gi0] - (acc[0][r] + xadd) * rdiv0;
    const size_t gi1 = (size_t)(cg + r) * N + m0 + 16 + lr;
    Td[gi1] = H[gi1] - (acc[1][r] + xadd) * rdiv1;
  }
}

// ---------------------------------------------------------------------------
// Apply BN+ReLU (+residual, +write output slice). grid 2048, 256 thr, float4.
// ---------------------------------------------------------------------------
template<bool RES>
__global__ __launch_bounds__(256) void k_apply(const float* __restrict__ T2,
                                               const float* __restrict__ bnpart,
                                               const float* __restrict__ gamma,
                                               const float* __restrict__ beta,
                                               float* __restrict__ H,
                                               float* __restrict__ Out) {
  __shared__ float rs[4], rq[4], bc[2];
  const int tid = threadIdx.x;
  const int f = (blockIdx.x * 256 + tid) * 4;
  const int c = (blockIdx.x >> 2) & 127;
  float s = bnpart[c * 512 + tid];
  float q = bnpart[c * 512 + 256 + tid];
#pragma unroll
  for (int o = 1; o <= 32; o <<= 1) { s += __shfl_xor(s, o, 64); q += __shfl_xor(q, o, 64); }
  if ((tid & 63) == 0) { rs[tid >> 6] = s; rq[tid >> 6] = q; }
  __syncthreads();
  if (tid == 0) {
    const float st = rs[0] + rs[1] + rs[2] + rs[3];
    const float qt = rq[0] + rq[1] + rq[2] + rq[3];
    const float inv = 1.0f / (B * N);
    const float mean = st * inv;
    const float var = qt * inv - mean * mean;   // biased, like torch BN
    const float sc = gamma[c] * rsqrtf(var + 1e-5f);
    bc[0] = sc;
    bc[1] = beta[c] - mean * sc;
  }
  __syncthreads();
  const float sc = bc[0], sh = bc[1];
  const float4 t = *(const float4*)&T2[f];
  float4 r;
  r.x = fmaxf(t.x * sc + sh, 0.f);
  r.y = fmaxf(t.y * sc + sh, 0.f);
  r.z = fmaxf(t.z * sc + sh, 0.f);
  r.w = fmaxf(t.w * sc + sh, 0.f);
  if (RES) {
    const float4 h = *(const float4*)&H[f];
    r.x += h.x; r.y += h.y; r.z += h.z; r.w += h.w;
    *(float4*)&H[f] = r;
    const int b = f >> 19;                // f / (C*N)
    const int rem = f & (C * N - 1);      // c*N + n
    *(float4*)&Out[(size_t)b * (4 * C * N) + rem] = r;
  } else {
    *(float4*)&H[f] = r;
  }
}

// ---------------------------------------------------------------------------
extern "C" void kernel_launch(void* const* d_in, const int* in_sizes, int n_in,
                              void* d_out, int out_size, void* d_ws, size_t ws_size,
                              hipStream_t stream) {
  const float* x    = (const float*)d_in[0];
  const int*   mask = (const int*)  d_in[1];
  const float* w1   = (const float*)d_in[2];
  const float* g1   = (const float*)d_in[3];
  const float* b1   = (const float*)d_in[4];
  const float* w2   = (const float*)d_in[5];
  const float* g2   = (const float*)d_in[6];
  const float* b2   = (const float*)d_in[7];
  const float* wqk  = (const float*)d_in[8];
  const float* wv   = (const float*)d_in[9];
  const float* bv   = (const float*)d_in[10];
  const float* wt   = (const float*)d_in[11];
  const float* bt   = (const float*)d_in[12];
  const float* sg   = (const float*)d_in[13];
  const float* sb   = (const float*)d_in[14];
  float* out = (float*)d_out;

  char* p = (char*)d_ws;
  auto alloc = [&](size_t bytes) { char* r = p; p += (bytes + 255) & ~(size_t)255; return r; };
  float*    H      = (float*)   alloc((size_t)B * C * N * 4);
  float*    T2     = (float*)   alloc((size_t)B * C * N * 4);
  float*    Td     = (float*)   alloc((size_t)B * C * N * 4);
  _Float16* QT     = (_Float16*)alloc((size_t)B * N * 32 * 2);
  _Float16* QTc    = (_Float16*)alloc((size_t)B * N * 32 * 2);   // contiguous with
  _Float16* XVc    = (_Float16*)alloc((size_t)B * C * N * 2);    // XVc: one memset
  float2*   rowst  = (float2*)  alloc((size_t)B * N * 8);
  float*    bnpart = (float*)   alloc((size_t)C * 512 * 4);
  int*      psum   = (int*)     alloc((size_t)B * N * 4);
  int*      nvb    = (int*)     alloc(256);
  float*    xvp    = (float*)   alloc((size_t)B * C * 128 * 4);
  float*    xvi    = (float*)   alloc((size_t)B * C * 4);
  _Float16* WF     = (_Float16*)alloc((size_t)180224 * 2);
  (void)ws_size;
  _Float16* wf1  = WF;
  _Float16* wf2  = WF + 16384;
  _Float16* wfv  = WF + 32768;
  _Float16* wft  = WF + 98304;
  _Float16* wfqk = WF + 163840;

  // ---- one-shot setup: weight convert, mask compaction, pad zeroing ----
  k_wcvt<<<176, 256, 0, stream>>>(w1, w2, wv, wt, wqk, WF);
  k_mask<<<B, 1024, 0, stream>>>(mask, psum, nvb);
  hipMemsetAsync(QTc, 0, (size_t)B * N * 32 * 2 + (size_t)B * C * N * 2, stream);

  // ---- stem: two conv1d(+BN+ReLU), MFMA, BN partials fused ----
  k_gwm<false, true><<<dim3(64, 2, B), 512, 0, stream>>>(wf1, x, nullptr, T2, bnpart);
  k_apply<false><<<2048, 256, 0, stream>>>(T2, bnpart, g1, b1, H, nullptr);
  k_gwm<false, true><<<dim3(64, 2, B), 512, 0, stream>>>(wf2, H, nullptr, T2, bnpart);
  k_apply<false><<<2048, 256, 0, stream>>>(T2, bnpart, g2, b2, H, nullptr);

  // ---- 4 chained offset-attention layers (compacted flash-style) ----
  for (int L = 0; L < 4; L++) {
    k_qv<<<dim3(128, B), 256, 0, stream>>>(wfv + (size_t)L * 16384, wfqk + (size_t)L * 4096,
                                           H, bv + L * C, mask, psum, XVc, QT, QTc, xvp);
    k_sm<<<dim3(257, B), 512, 0, stream>>>(QTc, nvb, xvp, xvi, rowst);
    k_pv<<<dim3(128, B), 512, 0, stream>>>(QT, QTc, XVc, H, mask, rowst, nvb, xvi, Td);
    k_gwm<true, true><<<dim3(64, 2, B), 512, 0, stream>>>(wft + (size_t)L * 16384, Td, bt + L * C, T2, bnpart);
    k_apply<true><<<2048, 256, 0, stream>>>(T2, bnpart, sg + L * C, sb + L * C, H, out + (size_t)L * C * N);
  }
}

// Round 6
// 446.468 us; speedup vs baseline: 1.1018x; 1.0617x over previous
//
#include <hip/hip_runtime.h>
#include <hip/hip_fp16.h>

constexpr int C = 128;
constexpr int N = 4096;
constexpr int B = 4;

typedef _Float16 f16x8 __attribute__((ext_vector_type(8)));
typedef _Float16 f16x4 __attribute__((ext_vector_type(4)));
typedef float    f32x4 __attribute__((ext_vector_type(4)));

// ---------------------------------------------------------------------------
// One-shot weight convert fp32 -> f16 into workspace, concatenated:
// [w1(16K) | w2(16K) | wv(64K) | wt(64K) | wqk(16K)] elements.
// grid 176, 256 thr; each thread converts one float4.
// ---------------------------------------------------------------------------
__global__ __launch_bounds__(256) void k_wcvt(const float* __restrict__ w1,
                                              const float* __restrict__ w2,
                                              const float* __restrict__ wv,
                                              const float* __restrict__ wt,
                                              const float* __restrict__ wqk,
                                              _Float16* __restrict__ WF) {
  const int g = blockIdx.x * 256 + threadIdx.x;   // float4 index
  const float* src; int off;
  if (g < 4096)       { src = w1;  off = g; }
  else if (g < 8192)  { src = w2;  off = g - 4096; }
  else if (g < 24576) { src = wv;  off = g - 8192; }
  else if (g < 40960) { src = wt;  off = g - 24576; }
  else                { src = wqk; off = g - 40960; }
  const float4 v = ((const float4*)src)[off];
  f16x4 h = {(_Float16)v.x, (_Float16)v.y, (_Float16)v.z, (_Float16)v.w};
  *(f16x4*)&WF[(size_t)g * 4] = h;
}

// ---------------------------------------------------------------------------
// Mask compaction: exclusive prefix sum of (mask!=0) per batch + valid count.
// grid B, 1024 thr (4 elements/thread).
// ---------------------------------------------------------------------------
__global__ __launch_bounds__(1024) void k_mask(const int* __restrict__ mask,
                                               int* __restrict__ psum,
                                               int* __restrict__ nvb) {
  const int b = blockIdx.x, tid = threadIdx.x;
  __shared__ int wsum[16];
  const int4 mv = *(const int4*)&mask[b * N + tid * 4];
  const int m0 = (mv.x != 0), m1 = (mv.y != 0), m2 = (mv.z != 0), m3 = (mv.w != 0);
  const int s0 = m0, s1 = s0 + m1, s2 = s1 + m2, s3 = s2 + m3;
  const int lane = tid & 63, w = tid >> 6;
  int sc = s3;
#pragma unroll
  for (int o = 1; o < 64; o <<= 1) {
    const int v = __shfl_up(sc, o, 64);
    if (lane >= o) sc += v;
  }
  if (lane == 63) wsum[w] = sc;
  __syncthreads();
  if (tid < 16) {
    int v = wsum[tid];
#pragma unroll
    for (int o = 1; o < 16; o <<= 1) {
      const int u = __shfl_up(v, o, 64);
      if (tid >= o) v += u;
    }
    wsum[tid] = v;
  }
  __syncthreads();
  const int excl = ((w > 0) ? wsum[w - 1] : 0) + sc - s3;
  int4 pv;
  pv.x = excl; pv.y = excl + s0; pv.z = excl + s1; pv.w = excl + s2;
  *(int4*)&psum[b * N + tid * 4] = pv;
  if (tid == 0) nvb[b] = wsum[15];
}

// ---------------------------------------------------------------------------
// MFMA projection GEMM. Y[b,o,n] = sum_c W[o,c]*X[b,c,n] (+bias), fp32 out.
// grid (N/64, 2, B), block 512.
// ---------------------------------------------------------------------------
template<bool BIAS, bool STAT>
__global__ __launch_bounds__(512) void k_gwm(const _Float16* __restrict__ WF,
                                             const float* __restrict__ X,
                                             const float* __restrict__ bias,
                                             float* __restrict__ Y,
                                             float* __restrict__ bnpart) {
  __shared__ _Float16 XT[64 * 136];          // [n][c], stride 136 (16B-aligned rows)
  __shared__ float statP[4][64], statQ[4][64];
  const int tid = threadIdx.x;
  const int n0 = blockIdx.x * 64, oh = blockIdx.y, b = blockIdx.z;
  const float* Xb = X + (size_t)(b * C) * N + n0;
#pragma unroll
  for (int i = 0; i < 4; i++) {              // 2048 float4: c=idx>>4, q=idx&15
    const int idx = tid + i * 512;
    const int c = idx >> 4, q = idx & 15;
    const float4 v = *(const float4*)&Xb[(size_t)c * N + q * 4];
    XT[(q * 4 + 0) * 136 + c] = (_Float16)v.x;
    XT[(q * 4 + 1) * 136 + c] = (_Float16)v.y;
    XT[(q * 4 + 2) * 136 + c] = (_Float16)v.z;
    XT[(q * 4 + 3) * 136 + c] = (_Float16)v.w;
  }
  __syncthreads();
  const int w = tid >> 6, lane = tid & 63, quad = lane >> 4, lr = lane & 15;
  const int nt = w & 3, og = w >> 2;
  const int ob[2] = {oh * 64 + og * 16, oh * 64 + (og + 2) * 16};
  f16x8 aW[2][4];
#pragma unroll
  for (int t = 0; t < 2; t++)
#pragma unroll
    for (int kc = 0; kc < 4; kc++)
      aW[t][kc] = *(const f16x8*)&WF[(size_t)(ob[t] + lr) * 128 + kc * 32 + quad * 8];
  f32x4 acc[2];
  acc[0] = (f32x4){0.f, 0.f, 0.f, 0.f};
  acc[1] = (f32x4){0.f, 0.f, 0.f, 0.f};
#pragma unroll
  for (int kc = 0; kc < 4; kc++) {
    const f16x8 bf = *(const f16x8*)&XT[(nt * 16 + lr) * 136 + kc * 32 + quad * 8];
    acc[0] = __builtin_amdgcn_mfma_f32_16x16x32_f16(aW[0][kc], bf, acc[0], 0, 0, 0);
    acc[1] = __builtin_amdgcn_mfma_f32_16x16x32_f16(aW[1][kc], bf, acc[1], 0, 0, 0);
  }
#pragma unroll
  for (int t = 0; t < 2; t++) {
#pragma unroll
    for (int r = 0; r < 4; r++) {
      const int o = ob[t] + quad * 4 + r;
      const float val = acc[t][r] + (BIAS ? bias[o] : 0.f);
      Y[(size_t)(b * C + o) * N + n0 + nt * 16 + lr] = val;
      if (STAT) {
        float s = val, q = val * val;
        s += __shfl_xor(s, 1, 64); q += __shfl_xor(q, 1, 64);
        s += __shfl_xor(s, 2, 64); q += __shfl_xor(q, 2, 64);
        s += __shfl_xor(s, 4, 64); q += __shfl_xor(q, 4, 64);
        s += __shfl_xor(s, 8, 64); q += __shfl_xor(q, 8, 64);
        if (lr == 0) { statP[nt][o - oh * 64] = s; statQ[nt][o - oh * 64] = q; }
      }
    }
  }
  if (STAT) {
    __syncthreads();
    if (tid < 64) {
      const int o = oh * 64 + tid;
      const float s = statP[0][tid] + statP[1][tid] + statP[2][tid] + statP[3][tid];
      const float q = statQ[0][tid] + statQ[1][tid] + statQ[2][tid] + statQ[3][tid];
      const int part = blockIdx.x * 4 + b;
      bnpart[o * 512 + part] = s;
      bnpart[o * 512 + 256 + part] = q;
    }
  }
}

// ---------------------------------------------------------------------------
// Fused XV + QT projection via MFMA.  Outputs:
//  - QT  [b][n][32]      (original n space; k_pv B-operand for all m columns)
//  - QTc [b][j][32]      (compacted: only valid n, j = psum[n]; pads zero)
//  - XVc [b][c][j]       (compacted XV, f16, N-stride rows; pads zero)
//  - xvp [(b*C+o)][128]  per-block partial sums of XV over INVALID n (f32)
// grid (N/32, B), block 256.
// ---------------------------------------------------------------------------
__global__ __launch_bounds__(256) void k_qv(const _Float16* __restrict__ WFv,
                                            const _Float16* __restrict__ WFqk,
                                            const float* __restrict__ X,
                                            const float* __restrict__ bv,
                                            const int* __restrict__ mask,
                                            const int* __restrict__ psum,
                                            _Float16* __restrict__ XVc,
                                            _Float16* __restrict__ QT,
                                            _Float16* __restrict__ QTc,
                                            float* __restrict__ xvp) {
  __shared__ _Float16 XT[32 * 136];
  __shared__ float SP[2][128];
  const int tid = threadIdx.x;
  const int n0 = blockIdx.x * 32, b = blockIdx.y;
  const float* Xb = X + (size_t)(b * C) * N + n0;
#pragma unroll
  for (int i = 0; i < 4; i++) {              // 1024 float4: c=idx>>3, q=idx&7
    const int idx = tid + i * 256;
    const int c = idx >> 3, q = idx & 7;
    const float4 v = *(const float4*)&Xb[(size_t)c * N + q * 4];
    XT[(q * 4 + 0) * 136 + c] = (_Float16)v.x;
    XT[(q * 4 + 1) * 136 + c] = (_Float16)v.y;
    XT[(q * 4 + 2) * 136 + c] = (_Float16)v.z;
    XT[(q * 4 + 3) * 136 + c] = (_Float16)v.w;
  }
  __syncthreads();
  const int w = tid >> 6, lane = tid & 63, quad = lane >> 4, lr = lane & 15;
  const int nt = w & 1, og = w >> 1;
  const int n = n0 + nt * 16 + lr;
  const int vld = mask[b * N + n] != 0;
  const int jc = psum[b * N + n];
  f32x4 acc[5];
  const _Float16* Aptr[5];
  int otl[5];
#pragma unroll
  for (int j = 0; j < 5; j++) {
    acc[j] = (f32x4){0.f, 0.f, 0.f, 0.f};
    const int ot = og + 2 * j;
    otl[j] = ot;
    Aptr[j] = (ot < 8) ? (WFv + (size_t)(ot * 16 + lr) * 128)
                       : (WFqk + (size_t)((ot - 8) * 16 + lr) * 128);
  }
#pragma unroll
  for (int kc = 0; kc < 4; kc++) {
    const f16x8 bf = *(const f16x8*)&XT[(nt * 16 + lr) * 136 + kc * 32 + quad * 8];
#pragma unroll
    for (int j = 0; j < 5; j++) {
      const f16x8 a = *(const f16x8*)&Aptr[j][kc * 32 + quad * 8];
      acc[j] = __builtin_amdgcn_mfma_f32_16x16x32_f16(a, bf, acc[j], 0, 0, 0);
    }
  }
#pragma unroll
  for (int j = 0; j < 5; j++) {
    const int ot = otl[j];
    if (ot < 8) {
      float v[4];
#pragma unroll
      for (int r = 0; r < 4; r++) v[r] = acc[j][r] + bv[ot * 16 + quad * 4 + r];
      if (vld) {
#pragma unroll
        for (int r = 0; r < 4; r++)
          XVc[(size_t)(b * C + ot * 16 + quad * 4 + r) * N + jc] = (_Float16)v[r];
      }
      float s[4];
#pragma unroll
      for (int r = 0; r < 4; r++) s[r] = vld ? 0.f : v[r];
#pragma unroll
      for (int o = 1; o <= 8; o <<= 1) {
#pragma unroll
        for (int r = 0; r < 4; r++) s[r] += __shfl_xor(s[r], o, 64);
      }
      if (lr == 0) {
#pragma unroll
        for (int r = 0; r < 4; r++) SP[nt][ot * 16 + quad * 4 + r] = s[r];
      }
    } else {
      f16x4 qv;
#pragma unroll
      for (int r = 0; r < 4; r++) qv[r] = (_Float16)acc[j][r];
      const int qo = (ot - 8) * 16 + quad * 4;
      *(f16x4*)&QT[((size_t)b * N + n) * 32 + qo] = qv;
      if (vld) *(f16x4*)&QTc[((size_t)b * N + jc) * 32 + qo] = qv;
    }
  }
  __syncthreads();
  if (tid < 128)
    xvp[(size_t)(b * C + tid) * 128 + blockIdx.x] = SP[0][tid] + SP[1][tid];
}

// ---------------------------------------------------------------------------
// Row stats over COMPACTED space, single-pass online softmax.
// 16 rows/block, pad-bias arithmetic (mrow<Nv).  Block bx==256 instead
// reduces xvp -> xvi.  rowst[b*N+row] = (rowmax, 1/rowsum).
// grid (257, B), block 512.
// ---------------------------------------------------------------------------
__global__ __launch_bounds__(512) void k_sm(const _Float16* __restrict__ QTc,
                                            const int* __restrict__ nvb,
                                            const float* __restrict__ xvp,
                                            float* __restrict__ xvi,
                                            float2* __restrict__ rowst) {
  const int b = blockIdx.y, tid = threadIdx.x;
  if (blockIdx.x == 256) {                   // xvi reduction block
    __shared__ float xr[128][4];
    const int c = tid >> 2, q = tid & 3;
    const float* src = xvp + (size_t)(b * C + c) * 128 + q * 32;
    float v = 0.f;
#pragma unroll
    for (int i = 0; i < 32; i++) v += src[i];
    xr[c][q] = v;
    __syncthreads();
    if (tid < 128) xvi[b * C + tid] = xr[tid][0] + xr[tid][1] + xr[tid][2] + xr[tid][3];
    return;
  }
  const int Nv = nvb[b];
  const int NvpB = (Nv + 63) & ~63;
  const int n0 = blockIdx.x * 16;
  if (n0 >= NvpB) return;
  __shared__ float redM[8][16], redS[8][16];
  const _Float16* Qb = QTc + (size_t)b * N * 32;
  const int w = tid >> 6, lane = tid & 63, quad = lane >> 4, lr = lane & 15;
  const f16x8 aF = *(const f16x8*)&Qb[(size_t)(n0 + lr) * 32 + quad * 8];
  float mx[4] = {-3e38f, -3e38f, -3e38f, -3e38f};
  float s[4] = {0.f, 0.f, 0.f, 0.f};
  for (int ms = 0; ms < NvpB; ms += 128) {   // 8 waves x 16 m-cols per iter
    const int mrow = ms + w * 16 + lr;
    const f16x8 bF = *(const f16x8*)&Qb[(size_t)mrow * 32 + quad * 8];
    f32x4 d = (f32x4){0.f, 0.f, 0.f, 0.f};
    d = __builtin_amdgcn_mfma_f32_16x16x32_f16(aF, bF, d, 0, 0, 0);
    const float bias = (mrow < Nv) ? 0.0f : -1e30f;
#pragma unroll
    for (int r = 0; r < 4; r++) {
      const float dv = d[r] + bias;
      if (dv > mx[r]) {                      // rare after warm-up (defer-max)
        s[r] *= __expf(mx[r] - dv);
        mx[r] = dv;
      }
      s[r] += __expf(dv - mx[r]);
    }
  }
  // merge (mx,s) across the 16 lr lanes (butterfly log-sum-exp)
#pragma unroll
  for (int r = 0; r < 4; r++) {
#pragma unroll
    for (int o = 1; o <= 8; o <<= 1) {
      const float mo = __shfl_xor(mx[r], o, 64);
      const float so = __shfl_xor(s[r], o, 64);
      const float mn = fmaxf(mx[r], mo);
      s[r] = s[r] * __expf(mx[r] - mn) + so * __expf(mo - mn);
      mx[r] = mn;
    }
  }
  if (lr == 0)
#pragma unroll
    for (int r = 0; r < 4; r++) {
      redM[w][quad * 4 + r] = mx[r];
      redS[w][quad * 4 + r] = s[r];
    }
  __syncthreads();
  if (tid < 16) {
    float M = redM[0][tid];
#pragma unroll
    for (int k = 1; k < 8; k++) M = fmaxf(M, redM[k][tid]);
    float tot = 0.f;
#pragma unroll
    for (int k = 0; k < 8; k++) tot += redS[k][tid] * __expf(redM[k][tid] - M);
    const int row = n0 + tid;
    const bool valid = row < Nv;
    float2 rv;
    rv.x = valid ? M : 1e30f;
    rv.y = valid ? (1.0f / tot) : 0.0f;
    rowst[b * N + row] = rv;
  }
}

// ---------------------------------------------------------------------------
// Fused Gram->exp->PV, R14: SWAPPED Gram operands.  E' = mfma(Q[n], Q[m])
// puts each thread's 4 P values at fixed m=lr, consecutive n=quad*4+r:
//  - P store is ONE f16x4 vector write into PsT[m][n] (was 4 scalar b16)
//  - consume's B-fragment read from PsT[lr*72+quad*8] is the exact MFMA
//    B layout (4x ds_read_b128, unchanged)
//  - B-operand Q[m] is block-constant -> hoisted out of the loop
// LDS instr/wave/step: 12 -> 9.  Everything else is the R1/R5-proven
// monolith: compacted n, m original, XVs/Ps double-buffer, direct Td write.
//   x_r = (acc + xvInvSum/4096) / (1e-9 + colS + ninv/4096)
// grid (N/32, B), block 512.
// ---------------------------------------------------------------------------
__global__ __launch_bounds__(512, 4) void k_pv(const _Float16* __restrict__ QT,
                                               const _Float16* __restrict__ QTc,
                                               const _Float16* __restrict__ XVc,
                                               const float* __restrict__ H,
                                               const int* __restrict__ mask,
                                               const float2* __restrict__ rowst,
                                               const int* __restrict__ nvb,
                                               const float* __restrict__ xvi,
                                               float* __restrict__ Td) {
  __shared__ _Float16 XVs[2][128 * 72];
  __shared__ _Float16 PsT[2][32 * 72];
  __shared__ float colPart[4][32];
  __shared__ float colS[32];
  const int tid = threadIdx.x;
  const int m0 = blockIdx.x * 32, b = blockIdx.y;
  const int Nv = nvb[b];
  const int ns = ((Nv + 63) & ~63) >> 6;
  const _Float16* Qa = QT + (size_t)b * N * 32;
  const _Float16* Qc = QTc + (size_t)b * N * 32;
  const _Float16* XVb = XVc + (size_t)(b * C) * N;
  const float2* rsB = rowst + (size_t)b * N;
  const int w = tid >> 6, lane = tid & 63, quad = lane >> 4, lr = lane & 15;
  const int msub = w & 1, nsub = w >> 1;
  // block-constant B-operand: Q at this block's m rows (original space)
  const f16x8 bGm = *(const f16x8*)&Qa[(size_t)(m0 + msub * 16 + lr) * 32 + quad * 8];
  const float vmb =
      (mask[b * N + m0 + msub * 16 + lr] != 0) ? 0.0f : -1e30f;  // per-thread m=lr
  const int sc0 = tid >> 3, sh0 = tid & 7;   // XV staging rows (2 vec/thread)
  const int sc1 = sc0 + 64;
  f32x4 acc[2];
  acc[0] = (f32x4){0.f, 0.f, 0.f, 0.f};
  acc[1] = (f32x4){0.f, 0.f, 0.f, 0.f};
  float cs = 0.f;                            // column-sum for m = lr (this msub)

  auto produce = [&](int k0, int bf) {
    // A-operand: Q at compacted n rows (varies per step)
    const f16x8 aGn = *(const f16x8*)&Qc[(size_t)(k0 + nsub * 16 + lr) * 32 + quad * 8];
    const f16x8 xv0 = *(const f16x8*)&XVb[(size_t)sc0 * N + k0 + sh0 * 8];
    const f16x8 xv1 = *(const f16x8*)&XVb[(size_t)sc1 * N + k0 + sh0 * 8];
    const int nb = k0 + nsub * 16 + quad * 4;          // this thread's 4 n values
    const float4 r01 = *(const float4*)&rsB[nb];       // (max0,ri0,max1,ri1)
    const float4 r23 = *(const float4*)&rsB[nb + 2];   // (max2,ri2,max3,ri3)
    f32x4 e = (f32x4){0.f, 0.f, 0.f, 0.f};
    e = __builtin_amdgcn_mfma_f32_16x16x32_f16(aGn, bGm, e, 0, 0, 0);
    *(f16x8*)&XVs[bf][sc0 * 72 + sh0 * 8] = xv0;
    *(f16x8*)&XVs[bf][sc1 * 72 + sh0 * 8] = xv1;
    const float p0 = __expf(e[0] - r01.x + vmb) * r01.y;  // pad rows: ri=0 -> 0
    const float p1 = __expf(e[1] - r01.z + vmb) * r01.w;
    const float p2 = __expf(e[2] - r23.x + vmb) * r23.y;
    const float p3 = __expf(e[3] - r23.z + vmb) * r23.w;
    cs += (p0 + p1) + (p2 + p3);
    f16x4 pp = {(_Float16)p0, (_Float16)p1, (_Float16)p2, (_Float16)p3};
    *(f16x4*)&PsT[bf][(msub * 16 + lr) * 72 + nsub * 16 + quad * 4] = pp;
  };
  auto consume = [&](int bf) {
    const int c0 = w * 16;
    const f16x8 a0 = *(const f16x8*)&XVs[bf][(c0 + lr) * 72 + quad * 8];
    const f16x8 a1 = *(const f16x8*)&XVs[bf][(c0 + lr) * 72 + 32 + quad * 8];
    const f16x8 b00 = *(const f16x8*)&PsT[bf][lr * 72 + quad * 8];
    const f16x8 b01 = *(const f16x8*)&PsT[bf][lr * 72 + 32 + quad * 8];
    const f16x8 b10 = *(const f16x8*)&PsT[bf][(16 + lr) * 72 + quad * 8];
    const f16x8 b11 = *(const f16x8*)&PsT[bf][(16 + lr) * 72 + 32 + quad * 8];
    acc[0] = __builtin_amdgcn_mfma_f32_16x16x32_f16(a0, b00, acc[0], 0, 0, 0);
    acc[0] = __builtin_amdgcn_mfma_f32_16x16x32_f16(a1, b01, acc[0], 0, 0, 0);
    acc[1] = __builtin_amdgcn_mfma_f32_16x16x32_f16(a0, b10, acc[1], 0, 0, 0);
    acc[1] = __builtin_amdgcn_mfma_f32_16x16x32_f16(a1, b11, acc[1], 0, 0, 0);
  };

  if (ns > 0) produce(0, 0);
  __syncthreads();
  for (int it = 0; it < ns; it += 2) {
    if (it + 1 < ns) produce((it + 1) * 64, 1);
    consume(0);
    __syncthreads();
    if (it + 1 < ns) {
      if (it + 2 < ns) produce((it + 2) * 64, 0);
      consume(1);
      __syncthreads();
    }
  }
  // reduce cs across the 4 quads (n-quarters of column m=lr)
  cs += __shfl_xor(cs, 16, 64);
  cs += __shfl_xor(cs, 32, 64);
  if (quad == 0) colPart[nsub][msub * 16 + lr] = cs;
  __syncthreads();
  if (tid < 32)
    colS[tid] = colPart[0][tid] + colPart[1][tid] + colPart[2][tid] + colPart[3][tid];
  __syncthreads();
  const float ninvq = (float)(N - Nv) * 0.000244140625f;   // ninv/4096
  const float rdiv0 = 1.0f / (1e-9f + colS[lr] + ninvq);
  const float rdiv1 = 1.0f / (1e-9f + colS[16 + lr] + ninvq);
  const int cg = b * C + w * 16 + quad * 4;
#pragma unroll
  for (int r = 0; r < 4; r++) {
    const float xadd = xvi[cg + r] * 0.000244140625f;      // xvInvSum/4096
    const size_t gi0 = (size_t)(cg + r) * N + m0 + lr;
    Td[gi0] = H[gi0] - (acc[0][r] + xadd) * rdiv0;
    const size_t gi1 = (size_t)(cg + r) * N + m0 + 16 + lr;
    Td[gi1] = H[gi1] - (acc[1][r] + xadd) * rdiv1;
  }
}

// ---------------------------------------------------------------------------
// Apply BN+ReLU (+residual, +write output slice). grid 2048, 256 thr, float4.
// ---------------------------------------------------------------------------
template<bool RES>
__global__ __launch_bounds__(256) void k_apply(const float* __restrict__ T2,
                                               const float* __restrict__ bnpart,
                                               const float* __restrict__ gamma,
                                               const float* __restrict__ beta,
                                               float* __restrict__ H,
                                               float* __restrict__ Out) {
  __shared__ float rs[4], rq[4], bc[2];
  const int tid = threadIdx.x;
  const int f = (blockIdx.x * 256 + tid) * 4;
  const int c = (blockIdx.x >> 2) & 127;
  float s = bnpart[c * 512 + tid];
  float q = bnpart[c * 512 + 256 + tid];
#pragma unroll
  for (int o = 1; o <= 32; o <<= 1) { s += __shfl_xor(s, o, 64); q += __shfl_xor(q, o, 64); }
  if ((tid & 63) == 0) { rs[tid >> 6] = s; rq[tid >> 6] = q; }
  __syncthreads();
  if (tid == 0) {
    const float st = rs[0] + rs[1] + rs[2] + rs[3];
    const float qt = rq[0] + rq[1] + rq[2] + rq[3];
    const float inv = 1.0f / (B * N);
    const float mean = st * inv;
    const float var = qt * inv - mean * mean;   // biased, like torch BN
    const float sc = gamma[c] * rsqrtf(var + 1e-5f);
    bc[0] = sc;
    bc[1] = beta[c] - mean * sc;
  }
  __syncthreads();
  const float sc = bc[0], sh = bc[1];
  const float4 t = *(const float4*)&T2[f];
  float4 r;
  r.x = fmaxf(t.x * sc + sh, 0.f);
  r.y = fmaxf(t.y * sc + sh, 0.f);
  r.z = fmaxf(t.z * sc + sh, 0.f);
  r.w = fmaxf(t.w * sc + sh, 0.f);
  if (RES) {
    const float4 h = *(const float4*)&H[f];
    r.x += h.x; r.y += h.y; r.z += h.z; r.w += h.w;
    *(float4*)&H[f] = r;
    const int b = f >> 19;                // f / (C*N)
    const int rem = f & (C * N - 1);      // c*N + n
    *(float4*)&Out[(size_t)b * (4 * C * N) + rem] = r;
  } else {
    *(float4*)&H[f] = r;
  }
}

// ---------------------------------------------------------------------------
extern "C" void kernel_launch(void* const* d_in, const int* in_sizes, int n_in,
                              void* d_out, int out_size, void* d_ws, size_t ws_size,
                              hipStream_t stream) {
  const float* x    = (const float*)d_in[0];
  const int*   mask = (const int*)  d_in[1];
  const float* w1   = (const float*)d_in[2];
  const float* g1   = (const float*)d_in[3];
  const float* b1   = (const float*)d_in[4];
  const float* w2   = (const float*)d_in[5];
  const float* g2   = (const float*)d_in[6];
  const float* b2   = (const float*)d_in[7];
  const float* wqk  = (const float*)d_in[8];
  const float* wv   = (const float*)d_in[9];
  const float* bv   = (const float*)d_in[10];
  const float* wt   = (const float*)d_in[11];
  const float* bt   = (const float*)d_in[12];
  const float* sg   = (const float*)d_in[13];
  const float* sb   = (const float*)d_in[14];
  float* out = (float*)d_out;

  char* p = (char*)d_ws;
  auto alloc = [&](size_t bytes) { char* r = p; p += (bytes + 255) & ~(size_t)255; return r; };
  float*    H      = (float*)   alloc((size_t)B * C * N * 4);
  float*    T2     = (float*)   alloc((size_t)B * C * N * 4);
  float*    Td     = (float*)   alloc((size_t)B * C * N * 4);
  _Float16* QT     = (_Float16*)alloc((size_t)B * N * 32 * 2);
  _Float16* QTc    = (_Float16*)alloc((size_t)B * N * 32 * 2);   // contiguous with
  _Float16* XVc    = (_Float16*)alloc((size_t)B * C * N * 2);    // XVc: one memset
  float2*   rowst  = (float2*)  alloc((size_t)B * N * 8);
  float*    bnpart = (float*)   alloc((size_t)C * 512 * 4);
  int*      psum   = (int*)     alloc((size_t)B * N * 4);
  int*      nvb    = (int*)     alloc(256);
  float*    xvp    = (float*)   alloc((size_t)B * C * 128 * 4);
  float*    xvi    = (float*)   alloc((size_t)B * C * 4);
  _Float16* WF     = (_Float16*)alloc((size_t)180224 * 2);
  (void)ws_size;
  _Float16* wf1  = WF;
  _Float16* wf2  = WF + 16384;
  _Float16* wfv  = WF + 32768;
  _Float16* wft  = WF + 98304;
  _Float16* wfqk = WF + 163840;

  // ---- one-shot setup: weight convert, mask compaction, pad zeroing ----
  k_wcvt<<<176, 256, 0, stream>>>(w1, w2, wv, wt, wqk, WF);
  k_mask<<<B, 1024, 0, stream>>>(mask, psum, nvb);
  hipMemsetAsync(QTc, 0, (size_t)B * N * 32 * 2 + (size_t)B * C * N * 2, stream);

  // ---- stem: two conv1d(+BN+ReLU), MFMA, BN partials fused ----
  k_gwm<false, true><<<dim3(64, 2, B), 512, 0, stream>>>(wf1, x, nullptr, T2, bnpart);
  k_apply<false><<<2048, 256, 0, stream>>>(T2, bnpart, g1, b1, H, nullptr);
  k_gwm<false, true><<<dim3(64, 2, B), 512, 0, stream>>>(wf2, H, nullptr, T2, bnpart);
  k_apply<false><<<2048, 256, 0, stream>>>(T2, bnpart, g2, b2, H, nullptr);

  // ---- 4 chained offset-attention layers (compacted flash-style) ----
  for (int L = 0; L < 4; L++) {
    k_qv<<<dim3(128, B), 256, 0, stream>>>(wfv + (size_t)L * 16384, wfqk + (size_t)L * 4096,
                                           H, bv + L * C, mask, psum, XVc, QT, QTc, xvp);
    k_sm<<<dim3(257, B), 512, 0, stream>>>(QTc, nvb, xvp, xvi, rowst);
    k_pv<<<dim3(128, B), 512, 0, stream>>>(QT, QTc, XVc, H, mask, rowst, nvb, xvi, Td);
    k_gwm<true, true><<<dim3(64, 2, B), 512, 0, stream>>>(wft + (size_t)L * 16384, Td, bt + L * C, T2, bnpart);
    k_apply<true><<<2048, 256, 0, stream>>>(T2, bnpart, sg + L * C, sb + L * C, H, out + (size_t)L * C * N);
  }
}

// Round 9
// 438.776 us; speedup vs baseline: 1.1211x; 1.0175x over previous
//
#include <hip/hip_runtime.h>
#include <hip/hip_fp16.h>

constexpr int C = 128;
constexpr int N = 4096;
constexpr int B = 4;

typedef _Float16 f16x8 __attribute__((ext_vector_type(8)));
typedef _Float16 f16x4 __attribute__((ext_vector_type(4)));
typedef float    f32x4 __attribute__((ext_vector_type(4)));

// ---------------------------------------------------------------------------
// One-shot weight convert fp32 -> f16 into workspace, concatenated:
// [w1(16K) | w2(16K) | wv(64K) | wt(64K) | wqk(16K)] elements.
// grid 176, 256 thr; each thread converts one float4.
// ---------------------------------------------------------------------------
__global__ __launch_bounds__(256) void k_wcvt(const float* __restrict__ w1,
                                              const float* __restrict__ w2,
                                              const float* __restrict__ wv,
                                              const float* __restrict__ wt,
                                              const float* __restrict__ wqk,
                                              _Float16* __restrict__ WF) {
  const int g = blockIdx.x * 256 + threadIdx.x;   // float4 index
  const float* src; int off;
  if (g < 4096)       { src = w1;  off = g; }
  else if (g < 8192)  { src = w2;  off = g - 4096; }
  else if (g < 24576) { src = wv;  off = g - 8192; }
  else if (g < 40960) { src = wt;  off = g - 24576; }
  else                { src = wqk; off = g - 40960; }
  const float4 v = ((const float4*)src)[off];
  f16x4 h = {(_Float16)v.x, (_Float16)v.y, (_Float16)v.z, (_Float16)v.w};
  *(f16x4*)&WF[(size_t)g * 4] = h;
}

// ---------------------------------------------------------------------------
// Mask compaction: exclusive prefix sum of (mask!=0) per batch + valid count.
// grid B, 1024 thr (4 elements/thread).
// ---------------------------------------------------------------------------
__global__ __launch_bounds__(1024) void k_mask(const int* __restrict__ mask,
                                               int* __restrict__ psum,
                                               int* __restrict__ nvb) {
  const int b = blockIdx.x, tid = threadIdx.x;
  __shared__ int wsum[16];
  const int4 mv = *(const int4*)&mask[b * N + tid * 4];
  const int m0 = (mv.x != 0), m1 = (mv.y != 0), m2 = (mv.z != 0), m3 = (mv.w != 0);
  const int s0 = m0, s1 = s0 + m1, s2 = s1 + m2, s3 = s2 + m3;
  const int lane = tid & 63, w = tid >> 6;
  int sc = s3;
#pragma unroll
  for (int o = 1; o < 64; o <<= 1) {
    const int v = __shfl_up(sc, o, 64);
    if (lane >= o) sc += v;
  }
  if (lane == 63) wsum[w] = sc;
  __syncthreads();
  if (tid < 16) {
    int v = wsum[tid];
#pragma unroll
    for (int o = 1; o < 16; o <<= 1) {
      const int u = __shfl_up(v, o, 64);
      if (tid >= o) v += u;
    }
    wsum[tid] = v;
  }
  __syncthreads();
  const int excl = ((w > 0) ? wsum[w - 1] : 0) + sc - s3;
  int4 pv;
  pv.x = excl; pv.y = excl + s0; pv.z = excl + s1; pv.w = excl + s2;
  *(int4*)&psum[b * N + tid * 4] = pv;
  if (tid == 0) nvb[b] = wsum[15];
}

// ---------------------------------------------------------------------------
// MFMA projection GEMM. Y[b,o,n] = sum_c W[o,c]*X[b,c,n] (+bias), f16 out.
// BN partials computed in fp32 BEFORE rounding.  Input fp32 or f16 (F16IN).
// grid (N/64, 2, B), block 512.
// ---------------------------------------------------------------------------
template<bool BIAS, bool STAT, bool F16IN>
__global__ __launch_bounds__(512) void k_gwm(const _Float16* __restrict__ WF,
                                             const void* __restrict__ Xv,
                                             const float* __restrict__ bias,
                                             _Float16* __restrict__ Y,
                                             float* __restrict__ bnpart) {
  __shared__ _Float16 XT[64 * 136];          // [n][c], stride 136 (16B-aligned rows)
  __shared__ float statP[4][64], statQ[4][64];
  const int tid = threadIdx.x;
  const int n0 = blockIdx.x * 64, oh = blockIdx.y, b = blockIdx.z;
  if constexpr (F16IN) {
    const _Float16* Xb = (const _Float16*)Xv + (size_t)(b * C) * N + n0;
#pragma unroll
    for (int i = 0; i < 2; i++) {            // 1024 f16x8: c=idx>>3, q=idx&7
      const int idx = tid + i * 512;
      const int c = idx >> 3, q = idx & 7;
      const f16x8 v = *(const f16x8*)&Xb[(size_t)c * N + q * 8];
#pragma unroll
      for (int e = 0; e < 8; e++) XT[(q * 8 + e) * 136 + c] = v[e];
    }
  } else {
    const float* Xb = (const float*)Xv + (size_t)(b * C) * N + n0;
#pragma unroll
    for (int i = 0; i < 4; i++) {            // 2048 float4: c=idx>>4, q=idx&15
      const int idx = tid + i * 512;
      const int c = idx >> 4, q = idx & 15;
      const float4 v = *(const float4*)&Xb[(size_t)c * N + q * 4];
      XT[(q * 4 + 0) * 136 + c] = (_Float16)v.x;
      XT[(q * 4 + 1) * 136 + c] = (_Float16)v.y;
      XT[(q * 4 + 2) * 136 + c] = (_Float16)v.z;
      XT[(q * 4 + 3) * 136 + c] = (_Float16)v.w;
    }
  }
  __syncthreads();
  const int w = tid >> 6, lane = tid & 63, quad = lane >> 4, lr = lane & 15;
  const int nt = w & 3, og = w >> 2;
  const int ob[2] = {oh * 64 + og * 16, oh * 64 + (og + 2) * 16};
  f16x8 aW[2][4];
#pragma unroll
  for (int t = 0; t < 2; t++)
#pragma unroll
    for (int kc = 0; kc < 4; kc++)
      aW[t][kc] = *(const f16x8*)&WF[(size_t)(ob[t] + lr) * 128 + kc * 32 + quad * 8];
  f32x4 acc[2];
  acc[0] = (f32x4){0.f, 0.f, 0.f, 0.f};
  acc[1] = (f32x4){0.f, 0.f, 0.f, 0.f};
#pragma unroll
  for (int kc = 0; kc < 4; kc++) {
    const f16x8 bf = *(const f16x8*)&XT[(nt * 16 + lr) * 136 + kc * 32 + quad * 8];
    acc[0] = __builtin_amdgcn_mfma_f32_16x16x32_f16(aW[0][kc], bf, acc[0], 0, 0, 0);
    acc[1] = __builtin_amdgcn_mfma_f32_16x16x32_f16(aW[1][kc], bf, acc[1], 0, 0, 0);
  }
#pragma unroll
  for (int t = 0; t < 2; t++) {
#pragma unroll
    for (int r = 0; r < 4; r++) {
      const int o = ob[t] + quad * 4 + r;
      const float val = acc[t][r] + (BIAS ? bias[o] : 0.f);
      Y[(size_t)(b * C + o) * N + n0 + nt * 16 + lr] = (_Float16)val;
      if (STAT) {
        float s = val, q = val * val;
        s += __shfl_xor(s, 1, 64); q += __shfl_xor(q, 1, 64);
        s += __shfl_xor(s, 2, 64); q += __shfl_xor(q, 2, 64);
        s += __shfl_xor(s, 4, 64); q += __shfl_xor(q, 4, 64);
        s += __shfl_xor(s, 8, 64); q += __shfl_xor(q, 8, 64);
        if (lr == 0) { statP[nt][o - oh * 64] = s; statQ[nt][o - oh * 64] = q; }
      }
    }
  }
  if (STAT) {
    __syncthreads();
    if (tid < 64) {
      const int o = oh * 64 + tid;
      const float s = statP[0][tid] + statP[1][tid] + statP[2][tid] + statP[3][tid];
      const float q = statQ[0][tid] + statQ[1][tid] + statQ[2][tid] + statQ[3][tid];
      const int part = blockIdx.x * 4 + b;
      bnpart[o * 512 + part] = s;
      bnpart[o * 512 + 256 + part] = q;
    }
  }
}

// ---------------------------------------------------------------------------
// Fused XV + QT projection via MFMA.  Outputs:
//  - QT  [b][n][32]      (original n space; k_pv B-operand for all m columns)
//  - QTc [b][j][32]      (compacted: only valid n, j = psum[n]; pads zero)
//  - XVc [b][c][j]       (compacted XV, f16, N-stride rows; pads zero)
//  - xvp [(b*C+o)][128]  per-block partial sums of XV over INVALID n (f32)
// grid (N/32, B), block 256.
// ---------------------------------------------------------------------------
__global__ __launch_bounds__(256) void k_qv(const _Float16* __restrict__ WFv,
                                            const _Float16* __restrict__ WFqk,
                                            const float* __restrict__ X,
                                            const float* __restrict__ bv,
                                            const int* __restrict__ mask,
                                            const int* __restrict__ psum,
                                            _Float16* __restrict__ XVc,
                                            _Float16* __restrict__ QT,
                                            _Float16* __restrict__ QTc,
                                            float* __restrict__ xvp) {
  __shared__ _Float16 XT[32 * 136];
  __shared__ float SP[2][128];
  const int tid = threadIdx.x;
  const int n0 = blockIdx.x * 32, b = blockIdx.y;
  const float* Xb = X + (size_t)(b * C) * N + n0;
#pragma unroll
  for (int i = 0; i < 4; i++) {              // 1024 float4: c=idx>>3, q=idx&7
    const int idx = tid + i * 256;
    const int c = idx >> 3, q = idx & 7;
    const float4 v = *(const float4*)&Xb[(size_t)c * N + q * 4];
    XT[(q * 4 + 0) * 136 + c] = (_Float16)v.x;
    XT[(q * 4 + 1) * 136 + c] = (_Float16)v.y;
    XT[(q * 4 + 2) * 136 + c] = (_Float16)v.z;
    XT[(q * 4 + 3) * 136 + c] = (_Float16)v.w;
  }
  __syncthreads();
  const int w = tid >> 6, lane = tid & 63, quad = lane >> 4, lr = lane & 15;
  const int nt = w & 1, og = w >> 1;
  const int n = n0 + nt * 16 + lr;
  const int vld = mask[b * N + n] != 0;
  const int jc = psum[b * N + n];
  f32x4 acc[5];
  const _Float16* Aptr[5];
  int otl[5];
#pragma unroll
  for (int j = 0; j < 5; j++) {
    acc[j] = (f32x4){0.f, 0.f, 0.f, 0.f};
    const int ot = og + 2 * j;
    otl[j] = ot;
    Aptr[j] = (ot < 8) ? (WFv + (size_t)(ot * 16 + lr) * 128)
                       : (WFqk + (size_t)((ot - 8) * 16 + lr) * 128);
  }
#pragma unroll
  for (int kc = 0; kc < 4; kc++) {
    const f16x8 bf = *(const f16x8*)&XT[(nt * 16 + lr) * 136 + kc * 32 + quad * 8];
#pragma unroll
    for (int j = 0; j < 5; j++) {
      const f16x8 a = *(const f16x8*)&Aptr[j][kc * 32 + quad * 8];
      acc[j] = __builtin_amdgcn_mfma_f32_16x16x32_f16(a, bf, acc[j], 0, 0, 0);
    }
  }
#pragma unroll
  for (int j = 0; j < 5; j++) {
    const int ot = otl[j];
    if (ot < 8) {
      float v[4];
#pragma unroll
      for (int r = 0; r < 4; r++) v[r] = acc[j][r] + bv[ot * 16 + quad * 4 + r];
      if (vld) {
#pragma unroll
        for (int r = 0; r < 4; r++)
          XVc[(size_t)(b * C + ot * 16 + quad * 4 + r) * N + jc] = (_Float16)v[r];
      }
      float s[4];
#pragma unroll
      for (int r = 0; r < 4; r++) s[r] = vld ? 0.f : v[r];
#pragma unroll
      for (int o = 1; o <= 8; o <<= 1) {
#pragma unroll
        for (int r = 0; r < 4; r++) s[r] += __shfl_xor(s[r], o, 64);
      }
      if (lr == 0) {
#pragma unroll
        for (int r = 0; r < 4; r++) SP[nt][ot * 16 + quad * 4 + r] = s[r];
      }
    } else {
      f16x4 qv;
#pragma unroll
      for (int r = 0; r < 4; r++) qv[r] = (_Float16)acc[j][r];
      const int qo = (ot - 8) * 16 + quad * 4;
      *(f16x4*)&QT[((size_t)b * N + n) * 32 + qo] = qv;
      if (vld) *(f16x4*)&QTc[((size_t)b * N + jc) * 32 + qo] = qv;
    }
  }
  __syncthreads();
  if (tid < 128)
    xvp[(size_t)(b * C + tid) * 128 + blockIdx.x] = SP[0][tid] + SP[1][tid];
}

// ---------------------------------------------------------------------------
// Row stats over COMPACTED space, single-pass online softmax.
// 16 rows/block, pad-bias arithmetic (mrow<Nv).  Block bx==256 instead
// reduces xvp -> xvi.  rowst[b*N+row] = (rowmax, 1/rowsum).
// grid (257, B), block 512.
// ---------------------------------------------------------------------------
__global__ __launch_bounds__(512) void k_sm(const _Float16* __restrict__ QTc,
                                            const int* __restrict__ nvb,
                                            const float* __restrict__ xvp,
                                            float* __restrict__ xvi,
                                            float2* __restrict__ rowst) {
  const int b = blockIdx.y, tid = threadIdx.x;
  if (blockIdx.x == 256) {                   // xvi reduction block
    __shared__ float xr[128][4];
    const int c = tid >> 2, q = tid & 3;
    const float* src = xvp + (size_t)(b * C + c) * 128 + q * 32;
    float v = 0.f;
#pragma unroll
    for (int i = 0; i < 32; i++) v += src[i];
    xr[c][q] = v;
    __syncthreads();
    if (tid < 128) xvi[b * C + tid] = xr[tid][0] + xr[tid][1] + xr[tid][2] + xr[tid][3];
    return;
  }
  const int Nv = nvb[b];
  const int NvpB = (Nv + 63) & ~63;
  const int n0 = blockIdx.x * 16;
  if (n0 >= NvpB) return;
  __shared__ float redM[8][16], redS[8][16];
  const _Float16* Qb = QTc + (size_t)b * N * 32;
  const int w = tid >> 6, lane = tid & 63, quad = lane >> 4, lr = lane & 15;
  const f16x8 aF = *(const f16x8*)&Qb[(size_t)(n0 + lr) * 32 + quad * 8];
  float mx[4] = {-3e38f, -3e38f, -3e38f, -3e38f};
  float s[4] = {0.f, 0.f, 0.f, 0.f};
  for (int ms = 0; ms < NvpB; ms += 128) {   // 8 waves x 16 m-cols per iter
    const int mrow = ms + w * 16 + lr;
    const f16x8 bF = *(const f16x8*)&Qb[(size_t)mrow * 32 + quad * 8];
    f32x4 d = (f32x4){0.f, 0.f, 0.f, 0.f};
    d = __builtin_amdgcn_mfma_f32_16x16x32_f16(aF, bF, d, 0, 0, 0);
    const float bias = (mrow < Nv) ? 0.0f : -1e30f;
#pragma unroll
    for (int r = 0; r < 4; r++) {
      const float dv = d[r] + bias;
      if (dv > mx[r]) {                      // rare after warm-up (defer-max)
        s[r] *= __expf(mx[r] - dv);
        mx[r] = dv;
      }
      s[r] += __expf(dv - mx[r]);
    }
  }
  // merge (mx,s) across the 16 lr lanes (butterfly log-sum-exp)
#pragma unroll
  for (int r = 0; r < 4; r++) {
#pragma unroll
    for (int o = 1; o <= 8; o <<= 1) {
      const float mo = __shfl_xor(mx[r], o, 64);
      const float so = __shfl_xor(s[r], o, 64);
      const float mn = fmaxf(mx[r], mo);
      s[r] = s[r] * __expf(mx[r] - mn) + so * __expf(mo - mn);
      mx[r] = mn;
    }
  }
  if (lr == 0)
#pragma unroll
    for (int r = 0; r < 4; r++) {
      redM[w][quad * 4 + r] = mx[r];
      redS[w][quad * 4 + r] = s[r];
    }
  __syncthreads();
  if (tid < 16) {
    float M = redM[0][tid];
#pragma unroll
    for (int k = 1; k < 8; k++) M = fmaxf(M, redM[k][tid]);
    float tot = 0.f;
#pragma unroll
    for (int k = 0; k < 8; k++) tot += redS[k][tid] * __expf(redM[k][tid] - M);
    const int row = n0 + tid;
    const bool valid = row < Nv;
    float2 rv;
    rv.x = valid ? M : 1e30f;
    rv.y = valid ? (1.0f / tot) : 0.0f;
    rowst[b * N + row] = rv;
  }
}

// ---------------------------------------------------------------------------
// Fused Gram->exp->PV with SWAPPED Gram operands (R6-proven, 446us).
// R16 change: Td written as f16 (it was rounded to f16 by the next GEMM's
// staging anyway; halves Td write+read traffic).
//   x_r = (acc + xvInvSum/4096) / (1e-9 + colS + ninv/4096)
// grid (N/32, B), block 512.
// ---------------------------------------------------------------------------
__global__ __launch_bounds__(512, 4) void k_pv(const _Float16* __restrict__ QT,
                                               const _Float16* __restrict__ QTc,
                                               const _Float16* __restrict__ XVc,
                                               const float* __restrict__ H,
                                               const int* __restrict__ mask,
                                               const float2* __restrict__ rowst,
                                               const int* __restrict__ nvb,
                                               const float* __restrict__ xvi,
                                               _Float16* __restrict__ Td) {
  __shared__ _Float16 XVs[2][128 * 72];
  __shared__ _Float16 PsT[2][32 * 72];
  __shared__ float colPart[4][32];
  __shared__ float colS[32];
  const int tid = threadIdx.x;
  const int m0 = blockIdx.x * 32, b = blockIdx.y;
  const int Nv = nvb[b];
  const int ns = ((Nv + 63) & ~63) >> 6;
  const _Float16* Qa = QT + (size_t)b * N * 32;
  const _Float16* Qc = QTc + (size_t)b * N * 32;
  const _Float16* XVb = XVc + (size_t)(b * C) * N;
  const float2* rsB = rowst + (size_t)b * N;
  const int w = tid >> 6, lane = tid & 63, quad = lane >> 4, lr = lane & 15;
  const int msub = w & 1, nsub = w >> 1;
  // block-constant B-operand: Q at this block's m rows (original space)
  const f16x8 bGm = *(const f16x8*)&Qa[(size_t)(m0 + msub * 16 + lr) * 32 + quad * 8];
  const float vmb =
      (mask[b * N + m0 + msub * 16 + lr] != 0) ? 0.0f : -1e30f;  // per-thread m=lr
  const int sc0 = tid >> 3, sh0 = tid & 7;   // XV staging rows (2 vec/thread)
  const int sc1 = sc0 + 64;
  f32x4 acc[2];
  acc[0] = (f32x4){0.f, 0.f, 0.f, 0.f};
  acc[1] = (f32x4){0.f, 0.f, 0.f, 0.f};
  float cs = 0.f;                            // column-sum for m = lr (this msub)

  auto produce = [&](int k0, int bf) {
    // A-operand: Q at compacted n rows (varies per step)
    const f16x8 aGn = *(const f16x8*)&Qc[(size_t)(k0 + nsub * 16 + lr) * 32 + quad * 8];
    const f16x8 xv0 = *(const f16x8*)&XVb[(size_t)sc0 * N + k0 + sh0 * 8];
    const f16x8 xv1 = *(const f16x8*)&XVb[(size_t)sc1 * N + k0 + sh0 * 8];
    const int nb = k0 + nsub * 16 + quad * 4;          // this thread's 4 n values
    const float4 r01 = *(const float4*)&rsB[nb];       // (max0,ri0,max1,ri1)
    const float4 r23 = *(const float4*)&rsB[nb + 2];   // (max2,ri2,max3,ri3)
    f32x4 e = (f32x4){0.f, 0.f, 0.f, 0.f};
    e = __builtin_amdgcn_mfma_f32_16x16x32_f16(aGn, bGm, e, 0, 0, 0);
    *(f16x8*)&XVs[bf][sc0 * 72 + sh0 * 8] = xv0;
    *(f16x8*)&XVs[bf][sc1 * 72 + sh0 * 8] = xv1;
    const float p0 = __expf(e[0] - r01.x + vmb) * r01.y;  // pad rows: ri=0 -> 0
    const float p1 = __expf(e[1] - r01.z + vmb) * r01.w;
    const float p2 = __expf(e[2] - r23.x + vmb) * r23.y;
    const float p3 = __expf(e[3] - r23.z + vmb) * r23.w;
    cs += (p0 + p1) + (p2 + p3);
    f16x4 pp = {(_Float16)p0, (_Float16)p1, (_Float16)p2, (_Float16)p3};
    *(f16x4*)&PsT[bf][(msub * 16 + lr) * 72 + nsub * 16 + quad * 4] = pp;
  };
  auto consume = [&](int bf) {
    const int c0 = w * 16;
    const f16x8 a0 = *(const f16x8*)&XVs[bf][(c0 + lr) * 72 + quad * 8];
    const f16x8 a1 = *(const f16x8*)&XVs[bf][(c0 + lr) * 72 + 32 + quad * 8];
    const f16x8 b00 = *(const f16x8*)&PsT[bf][lr * 72 + quad * 8];
    const f16x8 b01 = *(const f16x8*)&PsT[bf][lr * 72 + 32 + quad * 8];
    const f16x8 b10 = *(const f16x8*)&PsT[bf][(16 + lr) * 72 + quad * 8];
    const f16x8 b11 = *(const f16x8*)&PsT[bf][(16 + lr) * 72 + 32 + quad * 8];
    acc[0] = __builtin_amdgcn_mfma_f32_16x16x32_f16(a0, b00, acc[0], 0, 0, 0);
    acc[0] = __builtin_amdgcn_mfma_f32_16x16x32_f16(a1, b01, acc[0], 0, 0, 0);
    acc[1] = __builtin_amdgcn_mfma_f32_16x16x32_f16(a0, b10, acc[1], 0, 0, 0);
    acc[1] = __builtin_amdgcn_mfma_f32_16x16x32_f16(a1, b11, acc[1], 0, 0, 0);
  };

  if (ns > 0) produce(0, 0);
  __syncthreads();
  for (int it = 0; it < ns; it += 2) {
    if (it + 1 < ns) produce((it + 1) * 64, 1);
    consume(0);
    __syncthreads();
    if (it + 1 < ns) {
      if (it + 2 < ns) produce((it + 2) * 64, 0);
      consume(1);
      __syncthreads();
    }
  }
  // reduce cs across the 4 quads (n-quarters of column m=lr)
  cs += __shfl_xor(cs, 16, 64);
  cs += __shfl_xor(cs, 32, 64);
  if (quad == 0) colPart[nsub][msub * 16 + lr] = cs;
  __syncthreads();
  if (tid < 32)
    colS[tid] = colPart[0][tid] + colPart[1][tid] + colPart[2][tid] + colPart[3][tid];
  __syncthreads();
  const float ninvq = (float)(N - Nv) * 0.000244140625f;   // ninv/4096
  const float rdiv0 = 1.0f / (1e-9f + colS[lr] + ninvq);
  const float rdiv1 = 1.0f / (1e-9f + colS[16 + lr] + ninvq);
  const int cg = b * C + w * 16 + quad * 4;
#pragma unroll
  for (int r = 0; r < 4; r++) {
    const float xadd = xvi[cg + r] * 0.000244140625f;      // xvInvSum/4096
    const size_t gi0 = (size_t)(cg + r) * N + m0 + lr;
    Td[gi0] = (_Float16)(H[gi0] - (acc[0][r] + xadd) * rdiv0);
    const size_t gi1 = (size_t)(cg + r) * N + m0 + 16 + lr;
    Td[gi1] = (_Float16)(H[gi1] - (acc[1][r] + xadd) * rdiv1);
  }
}

// ---------------------------------------------------------------------------
// Apply BN+ReLU (+residual, +write output slice).  T2 is f16 (R16).
// grid 2048, 256 thr.
// ---------------------------------------------------------------------------
template<bool RES>
__global__ __launch_bounds__(256) void k_apply(const _Float16* __restrict__ T2,
                                               const float* __restrict__ bnpart,
                                               const float* __restrict__ gamma,
                                               const float* __restrict__ beta,
                                               float* __restrict__ H,
                                               float* __restrict__ Out) {
  __shared__ float rs[4], rq[4], bc[2];
  const int tid = threadIdx.x;
  const int f = (blockIdx.x * 256 + tid) * 4;
  const int c = (blockIdx.x >> 2) & 127;
  float s = bnpart[c * 512 + tid];
  float q = bnpart[c * 512 + 256 + tid];
#pragma unroll
  for (int o = 1; o <= 32; o <<= 1) { s += __shfl_xor(s, o, 64); q += __shfl_xor(q, o, 64); }
  if ((tid & 63) == 0) { rs[tid >> 6] = s; rq[tid >> 6] = q; }
  __syncthreads();
  if (tid == 0) {
    const float st = rs[0] + rs[1] + rs[2] + rs[3];
    const float qt = rq[0] + rq[1] + rq[2] + rq[3];
    const float inv = 1.0f / (B * N);
    const float mean = st * inv;
    const float var = qt * inv - mean * mean;   // biased, like torch BN
    const float sc = gamma[c] * rsqrtf(var + 1e-5f);
    bc[0] = sc;
    bc[1] = beta[c] - mean * sc;
  }
  __syncthreads();
  const float sc = bc[0], sh = bc[1];
  const f16x4 t = *(const f16x4*)&T2[f];
  float4 r;
  r.x = fmaxf((float)t[0] * sc + sh, 0.f);
  r.y = fmaxf((float)t[1] * sc + sh, 0.f);
  r.z = fmaxf((float)t[2] * sc + sh, 0.f);
  r.w = fmaxf((float)t[3] * sc + sh, 0.f);
  if (RES) {
    const float4 h = *(const float4*)&H[f];
    r.x += h.x; r.y += h.y; r.z += h.z; r.w += h.w;
    *(float4*)&H[f] = r;
    const int b = f >> 19;                // f / (C*N)
    const int rem = f & (C * N - 1);      // c*N + n
    *(float4*)&Out[(size_t)b * (4 * C * N) + rem] = r;
  } else {
    *(float4*)&H[f] = r;
  }
}

// ---------------------------------------------------------------------------
extern "C" void kernel_launch(void* const* d_in, const int* in_sizes, int n_in,
                              void* d_out, int out_size, void* d_ws, size_t ws_size,
                              hipStream_t stream) {
  const float* x    = (const float*)d_in[0];
  const int*   mask = (const int*)  d_in[1];
  const float* w1   = (const float*)d_in[2];
  const float* g1   = (const float*)d_in[3];
  const float* b1   = (const float*)d_in[4];
  const float* w2   = (const float*)d_in[5];
  const float* g2   = (const float*)d_in[6];
  const float* b2   = (const float*)d_in[7];
  const float* wqk  = (const float*)d_in[8];
  const float* wv   = (const float*)d_in[9];
  const float* bv   = (const float*)d_in[10];
  const float* wt   = (const float*)d_in[11];
  const float* bt   = (const float*)d_in[12];
  const float* sg   = (const float*)d_in[13];
  const float* sb   = (const float*)d_in[14];
  float* out = (float*)d_out;

  char* p = (char*)d_ws;
  auto alloc = [&](size_t bytes) { char* r = p; p += (bytes + 255) & ~(size_t)255; return r; };
  float*    H      = (float*)   alloc((size_t)B * C * N * 4);
  _Float16* T2h    = (_Float16*)alloc((size_t)B * C * N * 2);
  _Float16* Td16   = (_Float16*)alloc((size_t)B * C * N * 2);
  _Float16* QT     = (_Float16*)alloc((size_t)B * N * 32 * 2);
  _Float16* QTc    = (_Float16*)alloc((size_t)B * N * 32 * 2);   // contiguous with
  _Float16* XVc    = (_Float16*)alloc((size_t)B * C * N * 2);    // XVc: one memset
  float2*   rowst  = (float2*)  alloc((size_t)B * N * 8);
  float*    bnpart = (float*)   alloc((size_t)C * 512 * 4);
  int*      psum   = (int*)     alloc((size_t)B * N * 4);
  int*      nvb    = (int*)     alloc(256);
  float*    xvp    = (float*)   alloc((size_t)B * C * 128 * 4);
  float*    xvi    = (float*)   alloc((size_t)B * C * 4);
  _Float16* WF     = (_Float16*)alloc((size_t)180224 * 2);
  (void)ws_size;
  _Float16* wf1  = WF;
  _Float16* wf2  = WF + 16384;
  _Float16* wfv  = WF + 32768;
  _Float16* wft  = WF + 98304;
  _Float16* wfqk = WF + 163840;

  // ---- one-shot setup: weight convert, mask compaction, pad zeroing ----
  k_wcvt<<<176, 256, 0, stream>>>(w1, w2, wv, wt, wqk, WF);
  k_mask<<<B, 1024, 0, stream>>>(mask, psum, nvb);
  hipMemsetAsync(QTc, 0, (size_t)B * N * 32 * 2 + (size_t)B * C * N * 2, stream);

  // ---- stem: two conv1d(+BN+ReLU), MFMA, BN partials fused ----
  k_gwm<false, true, false><<<dim3(64, 2, B), 512, 0, stream>>>(wf1, x, nullptr, T2h, bnpart);
  k_apply<false><<<2048, 256, 0, stream>>>(T2h, bnpart, g1, b1, H, nullptr);
  k_gwm<false, true, false><<<dim3(64, 2, B), 512, 0, stream>>>(wf2, H, nullptr, T2h, bnpart);
  k_apply<false><<<2048, 256, 0, stream>>>(T2h, bnpart, g2, b2, H, nullptr);

  // ---- 4 chained offset-attention layers (compacted flash-style) ----
  for (int L = 0; L < 4; L++) {
    k_qv<<<dim3(128, B), 256, 0, stream>>>(wfv + (size_t)L * 16384, wfqk + (size_t)L * 4096,
                                           H, bv + L * C, mask, psum, XVc, QT, QTc, xvp);
    k_sm<<<dim3(257, B), 512, 0, stream>>>(QTc, nvb, xvp, xvi, rowst);
    k_pv<<<dim3(128, B), 512, 0, stream>>>(QT, QTc, XVc, H, mask, rowst, nvb, xvi, Td16);
    k_gwm<true, true, true><<<dim3(64, 2, B), 512, 0, stream>>>(wft + (size_t)L * 16384, Td16, bt + L * C, T2h, bnpart);
    k_apply<true><<<2048, 256, 0, stream>>>(T2h, bnpart, sg + L * C, sb + L * C, H, out + (size_t)L * C * N);
  }
}

// Round 10
// 411.556 us; speedup vs baseline: 1.1952x; 1.0661x over previous
//
#include <hip/hip_runtime.h>
#include <hip/hip_fp16.h>

constexpr int C = 128;
constexpr int N = 4096;
constexpr int B = 4;

typedef _Float16 f16x8 __attribute__((ext_vector_type(8)));
typedef _Float16 f16x4 __attribute__((ext_vector_type(4)));
typedef float    f32x4 __attribute__((ext_vector_type(4)));

// ---------------------------------------------------------------------------
// One-shot weight convert fp32 -> f16 into workspace, concatenated:
// [w1(16K) | w2(16K) | wv(64K) | wt(64K) | wqk(16K)] elements.
// grid 176, 256 thr; each thread converts one float4.
// ---------------------------------------------------------------------------
__global__ __launch_bounds__(256) void k_wcvt(const float* __restrict__ w1,
                                              const float* __restrict__ w2,
                                              const float* __restrict__ wv,
                                              const float* __restrict__ wt,
                                              const float* __restrict__ wqk,
                                              _Float16* __restrict__ WF) {
  const int g = blockIdx.x * 256 + threadIdx.x;   // float4 index
  const float* src; int off;
  if (g < 4096)       { src = w1;  off = g; }
  else if (g < 8192)  { src = w2;  off = g - 4096; }
  else if (g < 24576) { src = wv;  off = g - 8192; }
  else if (g < 40960) { src = wt;  off = g - 24576; }
  else                { src = wqk; off = g - 40960; }
  const float4 v = ((const float4*)src)[off];
  f16x4 h = {(_Float16)v.x, (_Float16)v.y, (_Float16)v.z, (_Float16)v.w};
  *(f16x4*)&WF[(size_t)g * 4] = h;
}

// ---------------------------------------------------------------------------
// Mask compaction: exclusive prefix sum of (mask!=0) per batch + valid count.
// grid B, 1024 thr (4 elements/thread).
// ---------------------------------------------------------------------------
__global__ __launch_bounds__(1024) void k_mask(const int* __restrict__ mask,
                                               int* __restrict__ psum,
                                               int* __restrict__ nvb) {
  const int b = blockIdx.x, tid = threadIdx.x;
  __shared__ int wsum[16];
  const int4 mv = *(const int4*)&mask[b * N + tid * 4];
  const int m0 = (mv.x != 0), m1 = (mv.y != 0), m2 = (mv.z != 0), m3 = (mv.w != 0);
  const int s0 = m0, s1 = s0 + m1, s2 = s1 + m2, s3 = s2 + m3;
  const int lane = tid & 63, w = tid >> 6;
  int sc = s3;
#pragma unroll
  for (int o = 1; o < 64; o <<= 1) {
    const int v = __shfl_up(sc, o, 64);
    if (lane >= o) sc += v;
  }
  if (lane == 63) wsum[w] = sc;
  __syncthreads();
  if (tid < 16) {
    int v = wsum[tid];
#pragma unroll
    for (int o = 1; o < 16; o <<= 1) {
      const int u = __shfl_up(v, o, 64);
      if (tid >= o) v += u;
    }
    wsum[tid] = v;
  }
  __syncthreads();
  const int excl = ((w > 0) ? wsum[w - 1] : 0) + sc - s3;
  int4 pv;
  pv.x = excl; pv.y = excl + s0; pv.z = excl + s1; pv.w = excl + s2;
  *(int4*)&psum[b * N + tid * 4] = pv;
  if (tid == 0) nvb[b] = wsum[15];
}

// ---------------------------------------------------------------------------
// MFMA projection GEMM (stem only now). Y f16 out, BN partials in fp32.
// bnpart layout: [o][1024]: sums at [part], squares at [512+part], part<256.
// grid (N/64, 2, B), block 512.
// ---------------------------------------------------------------------------
template<bool BIAS, bool STAT, bool F16IN>
__global__ __launch_bounds__(512) void k_gwm(const _Float16* __restrict__ WF,
                                             const void* __restrict__ Xv,
                                             const float* __restrict__ bias,
                                             _Float16* __restrict__ Y,
                                             float* __restrict__ bnpart) {
  __shared__ _Float16 XT[64 * 136];          // [n][c], stride 136 (16B-aligned rows)
  __shared__ float statP[4][64], statQ[4][64];
  const int tid = threadIdx.x;
  const int n0 = blockIdx.x * 64, oh = blockIdx.y, b = blockIdx.z;
  if constexpr (F16IN) {
    const _Float16* Xb = (const _Float16*)Xv + (size_t)(b * C) * N + n0;
#pragma unroll
    for (int i = 0; i < 2; i++) {            // 1024 f16x8: c=idx>>3, q=idx&7
      const int idx = tid + i * 512;
      const int c = idx >> 3, q = idx & 7;
      const f16x8 v = *(const f16x8*)&Xb[(size_t)c * N + q * 8];
#pragma unroll
      for (int e = 0; e < 8; e++) XT[(q * 8 + e) * 136 + c] = v[e];
    }
  } else {
    const float* Xb = (const float*)Xv + (size_t)(b * C) * N + n0;
#pragma unroll
    for (int i = 0; i < 4; i++) {            // 2048 float4: c=idx>>4, q=idx&15
      const int idx = tid + i * 512;
      const int c = idx >> 4, q = idx & 15;
      const float4 v = *(const float4*)&Xb[(size_t)c * N + q * 4];
      XT[(q * 4 + 0) * 136 + c] = (_Float16)v.x;
      XT[(q * 4 + 1) * 136 + c] = (_Float16)v.y;
      XT[(q * 4 + 2) * 136 + c] = (_Float16)v.z;
      XT[(q * 4 + 3) * 136 + c] = (_Float16)v.w;
    }
  }
  __syncthreads();
  const int w = tid >> 6, lane = tid & 63, quad = lane >> 4, lr = lane & 15;
  const int nt = w & 3, og = w >> 2;
  const int ob[2] = {oh * 64 + og * 16, oh * 64 + (og + 2) * 16};
  f16x8 aW[2][4];
#pragma unroll
  for (int t = 0; t < 2; t++)
#pragma unroll
    for (int kc = 0; kc < 4; kc++)
      aW[t][kc] = *(const f16x8*)&WF[(size_t)(ob[t] + lr) * 128 + kc * 32 + quad * 8];
  f32x4 acc[2];
  acc[0] = (f32x4){0.f, 0.f, 0.f, 0.f};
  acc[1] = (f32x4){0.f, 0.f, 0.f, 0.f};
#pragma unroll
  for (int kc = 0; kc < 4; kc++) {
    const f16x8 bf = *(const f16x8*)&XT[(nt * 16 + lr) * 136 + kc * 32 + quad * 8];
    acc[0] = __builtin_amdgcn_mfma_f32_16x16x32_f16(aW[0][kc], bf, acc[0], 0, 0, 0);
    acc[1] = __builtin_amdgcn_mfma_f32_16x16x32_f16(aW[1][kc], bf, acc[1], 0, 0, 0);
  }
#pragma unroll
  for (int t = 0; t < 2; t++) {
#pragma unroll
    for (int r = 0; r < 4; r++) {
      const int o = ob[t] + quad * 4 + r;
      const float val = acc[t][r] + (BIAS ? bias[o] : 0.f);
      Y[(size_t)(b * C + o) * N + n0 + nt * 16 + lr] = (_Float16)val;
      if (STAT) {
        float s = val, q = val * val;
        s += __shfl_xor(s, 1, 64); q += __shfl_xor(q, 1, 64);
        s += __shfl_xor(s, 2, 64); q += __shfl_xor(q, 2, 64);
        s += __shfl_xor(s, 4, 64); q += __shfl_xor(q, 4, 64);
        s += __shfl_xor(s, 8, 64); q += __shfl_xor(q, 8, 64);
        if (lr == 0) { statP[nt][o - oh * 64] = s; statQ[nt][o - oh * 64] = q; }
      }
    }
  }
  if (STAT) {
    __syncthreads();
    if (tid < 64) {
      const int o = oh * 64 + tid;
      const float s = statP[0][tid] + statP[1][tid] + statP[2][tid] + statP[3][tid];
      const float q = statQ[0][tid] + statQ[1][tid] + statQ[2][tid] + statQ[3][tid];
      const int part = blockIdx.x * 4 + b;
      bnpart[o * 1024 + part] = s;
      bnpart[o * 1024 + 512 + part] = q;
    }
  }
}

// ---------------------------------------------------------------------------
// Fused XV + QT projection via MFMA.  Outputs:
//  - QT  [b][n][32]      (original n space; k_pv B-operand for all m columns)
//  - QTc [b][j][32]      (compacted: only valid n, j = psum[n]; pads zero)
//  - XVc [b][c][j]       (compacted XV, f16, N-stride rows; pads zero)
//  - xvp [(b*C+o)][128]  per-block partial sums of XV over INVALID n (f32)
// grid (N/32, B), block 256.
// ---------------------------------------------------------------------------
__global__ __launch_bounds__(256) void k_qv(const _Float16* __restrict__ WFv,
                                            const _Float16* __restrict__ WFqk,
                                            const float* __restrict__ X,
                                            const float* __restrict__ bv,
                                            const int* __restrict__ mask,
                                            const int* __restrict__ psum,
                                            _Float16* __restrict__ XVc,
                                            _Float16* __restrict__ QT,
                                            _Float16* __restrict__ QTc,
                                            float* __restrict__ xvp) {
  __shared__ _Float16 XT[32 * 136];
  __shared__ float SP[2][128];
  const int tid = threadIdx.x;
  const int n0 = blockIdx.x * 32, b = blockIdx.y;
  const float* Xb = X + (size_t)(b * C) * N + n0;
#pragma unroll
  for (int i = 0; i < 4; i++) {              // 1024 float4: c=idx>>3, q=idx&7
    const int idx = tid + i * 256;
    const int c = idx >> 3, q = idx & 7;
    const float4 v = *(const float4*)&Xb[(size_t)c * N + q * 4];
    XT[(q * 4 + 0) * 136 + c] = (_Float16)v.x;
    XT[(q * 4 + 1) * 136 + c] = (_Float16)v.y;
    XT[(q * 4 + 2) * 136 + c] = (_Float16)v.z;
    XT[(q * 4 + 3) * 136 + c] = (_Float16)v.w;
  }
  __syncthreads();
  const int w = tid >> 6, lane = tid & 63, quad = lane >> 4, lr = lane & 15;
  const int nt = w & 1, og = w >> 1;
  const int n = n0 + nt * 16 + lr;
  const int vld = mask[b * N + n] != 0;
  const int jc = psum[b * N + n];
  f32x4 acc[5];
  const _Float16* Aptr[5];
  int otl[5];
#pragma unroll
  for (int j = 0; j < 5; j++) {
    acc[j] = (f32x4){0.f, 0.f, 0.f, 0.f};
    const int ot = og + 2 * j;
    otl[j] = ot;
    Aptr[j] = (ot < 8) ? (WFv + (size_t)(ot * 16 + lr) * 128)
                       : (WFqk + (size_t)((ot - 8) * 16 + lr) * 128);
  }
#pragma unroll
  for (int kc = 0; kc < 4; kc++) {
    const f16x8 bf = *(const f16x8*)&XT[(nt * 16 + lr) * 136 + kc * 32 + quad * 8];
#pragma unroll
    for (int j = 0; j < 5; j++) {
      const f16x8 a = *(const f16x8*)&Aptr[j][kc * 32 + quad * 8];
      acc[j] = __builtin_amdgcn_mfma_f32_16x16x32_f16(a, bf, acc[j], 0, 0, 0);
    }
  }
#pragma unroll
  for (int j = 0; j < 5; j++) {
    const int ot = otl[j];
    if (ot < 8) {
      float v[4];
#pragma unroll
      for (int r = 0; r < 4; r++) v[r] = acc[j][r] + bv[ot * 16 + quad * 4 + r];
      if (vld) {
#pragma unroll
        for (int r = 0; r < 4; r++)
          XVc[(size_t)(b * C + ot * 16 + quad * 4 + r) * N + jc] = (_Float16)v[r];
      }
      float s[4];
#pragma unroll
      for (int r = 0; r < 4; r++) s[r] = vld ? 0.f : v[r];
#pragma unroll
      for (int o = 1; o <= 8; o <<= 1) {
#pragma unroll
        for (int r = 0; r < 4; r++) s[r] += __shfl_xor(s[r], o, 64);
      }
      if (lr == 0) {
#pragma unroll
        for (int r = 0; r < 4; r++) SP[nt][ot * 16 + quad * 4 + r] = s[r];
      }
    } else {
      f16x4 qv;
#pragma unroll
      for (int r = 0; r < 4; r++) qv[r] = (_Float16)acc[j][r];
      const int qo = (ot - 8) * 16 + quad * 4;
      *(f16x4*)&QT[((size_t)b * N + n) * 32 + qo] = qv;
      if (vld) *(f16x4*)&QTc[((size_t)b * N + jc) * 32 + qo] = qv;
    }
  }
  __syncthreads();
  if (tid < 128)
    xvp[(size_t)(b * C + tid) * 128 + blockIdx.x] = SP[0][tid] + SP[1][tid];
}

// ---------------------------------------------------------------------------
// Row stats over COMPACTED space, single-pass online softmax.
// 16 rows/block, pad-bias arithmetic (mrow<Nv).  Block bx==256 instead
// reduces xvp -> xvi.  rowst[b*N+row] = (rowmax, 1/rowsum).
// grid (257, B), block 512.
// ---------------------------------------------------------------------------
__global__ __launch_bounds__(512) void k_sm(const _Float16* __restrict__ QTc,
                                            const int* __restrict__ nvb,
                                            const float* __restrict__ xvp,
                                            float* __restrict__ xvi,
                                            float2* __restrict__ rowst) {
  const int b = blockIdx.y, tid = threadIdx.x;
  if (blockIdx.x == 256) {                   // xvi reduction block
    __shared__ float xr[128][4];
    const int c = tid >> 2, q = tid & 3;
    const float* src = xvp + (size_t)(b * C + c) * 128 + q * 32;
    float v = 0.f;
#pragma unroll
    for (int i = 0; i < 32; i++) v += src[i];
    xr[c][q] = v;
    __syncthreads();
    if (tid < 128) xvi[b * C + tid] = xr[tid][0] + xr[tid][1] + xr[tid][2] + xr[tid][3];
    return;
  }
  const int Nv = nvb[b];
  const int NvpB = (Nv + 63) & ~63;
  const int n0 = blockIdx.x * 16;
  if (n0 >= NvpB) return;
  __shared__ float redM[8][16], redS[8][16];
  const _Float16* Qb = QTc + (size_t)b * N * 32;
  const int w = tid >> 6, lane = tid & 63, quad = lane >> 4, lr = lane & 15;
  const f16x8 aF = *(const f16x8*)&Qb[(size_t)(n0 + lr) * 32 + quad * 8];
  float mx[4] = {-3e38f, -3e38f, -3e38f, -3e38f};
  float s[4] = {0.f, 0.f, 0.f, 0.f};
  for (int ms = 0; ms < NvpB; ms += 128) {   // 8 waves x 16 m-cols per iter
    const int mrow = ms + w * 16 + lr;
    const f16x8 bF = *(const f16x8*)&Qb[(size_t)mrow * 32 + quad * 8];
    f32x4 d = (f32x4){0.f, 0.f, 0.f, 0.f};
    d = __builtin_amdgcn_mfma_f32_16x16x32_f16(aF, bF, d, 0, 0, 0);
    const float bias = (mrow < Nv) ? 0.0f : -1e30f;
#pragma unroll
    for (int r = 0; r < 4; r++) {
      const float dv = d[r] + bias;
      if (dv > mx[r]) {                      // rare after warm-up (defer-max)
        s[r] *= __expf(mx[r] - dv);
        mx[r] = dv;
      }
      s[r] += __expf(dv - mx[r]);
    }
  }
  // merge (mx,s) across the 16 lr lanes (butterfly log-sum-exp)
#pragma unroll
  for (int r = 0; r < 4; r++) {
#pragma unroll
    for (int o = 1; o <= 8; o <<= 1) {
      const float mo = __shfl_xor(mx[r], o, 64);
      const float so = __shfl_xor(s[r], o, 64);
      const float mn = fmaxf(mx[r], mo);
      s[r] = s[r] * __expf(mx[r] - mn) + so * __expf(mo - mn);
      mx[r] = mn;
    }
  }
  if (lr == 0)
#pragma unroll
    for (int r = 0; r < 4; r++) {
      redM[w][quad * 4 + r] = mx[r];
      redS[w][quad * 4 + r] = s[r];
    }
  __syncthreads();
  if (tid < 16) {
    float M = redM[0][tid];
#pragma unroll
    for (int k = 1; k < 8; k++) M = fmaxf(M, redM[k][tid]);
    float tot = 0.f;
#pragma unroll
    for (int k = 0; k < 8; k++) tot += redS[k][tid] * __expf(redM[k][tid] - M);
    const int row = n0 + tid;
    const bool valid = row < Nv;
    float2 rv;
    rv.x = valid ? M : 1e30f;
    rv.y = valid ? (1.0f / tot) : 0.0f;
    rowst[b * N + row] = rv;
  }
}

// ---------------------------------------------------------------------------
// Fused Gram->exp->PV ->>> + wt-GEMM + BN partials (R17).
// The PV accumulator IS the full Td tile [128c x 32m] for this block, so the
// following wt projection (out = wt·td + bt) runs in the epilogue off an
// 8.7KB LDS tile (reusing XVs).  Td never touches HBM; the k_gwm launch and
// its staging vanish.  BN partials: 512 contention-free parts (b*128+bx).
//   td = H - (acc + xvInvSum/4096) / (1e-9 + colS + ninv/4096)
// grid (N/32, B), block 512.
// ---------------------------------------------------------------------------
__global__ __launch_bounds__(512, 4) void k_pv(const _Float16* __restrict__ QT,
                                               const _Float16* __restrict__ QTc,
                                               const _Float16* __restrict__ XVc,
                                               const _Float16* __restrict__ WFt,
                                               const float* __restrict__ H,
                                               const int* __restrict__ mask,
                                               const float2* __restrict__ rowst,
                                               const int* __restrict__ nvb,
                                               const float* __restrict__ xvi,
                                               const float* __restrict__ bt,
                                               _Float16* __restrict__ T2h,
                                               float* __restrict__ bnpart) {
  __shared__ _Float16 XVs[2][128 * 72];
  __shared__ _Float16 PsT[2][32 * 72];
  __shared__ float colPart[4][32];
  __shared__ float colS[32];
  const int tid = threadIdx.x;
  const int m0 = blockIdx.x * 32, b = blockIdx.y;
  const int Nv = nvb[b];
  const int ns = ((Nv + 63) & ~63) >> 6;
  const _Float16* Qa = QT + (size_t)b * N * 32;
  const _Float16* Qc = QTc + (size_t)b * N * 32;
  const _Float16* XVb = XVc + (size_t)(b * C) * N;
  const float2* rsB = rowst + (size_t)b * N;
  const int w = tid >> 6, lane = tid & 63, quad = lane >> 4, lr = lane & 15;
  const int msub = w & 1, nsub = w >> 1;
  // block-constant B-operand: Q at this block's m rows (original space)
  const f16x8 bGm = *(const f16x8*)&Qa[(size_t)(m0 + msub * 16 + lr) * 32 + quad * 8];
  const float vmb =
      (mask[b * N + m0 + msub * 16 + lr] != 0) ? 0.0f : -1e30f;  // per-thread m=lr
  const int sc0 = tid >> 3, sh0 = tid & 7;   // XV staging rows (2 vec/thread)
  const int sc1 = sc0 + 64;
  f32x4 acc[2];
  acc[0] = (f32x4){0.f, 0.f, 0.f, 0.f};
  acc[1] = (f32x4){0.f, 0.f, 0.f, 0.f};
  float cs = 0.f;                            // column-sum for m = lr (this msub)

  auto produce = [&](int k0, int bf) {
    // A-operand: Q at compacted n rows (varies per step)
    const f16x8 aGn = *(const f16x8*)&Qc[(size_t)(k0 + nsub * 16 + lr) * 32 + quad * 8];
    const f16x8 xv0 = *(const f16x8*)&XVb[(size_t)sc0 * N + k0 + sh0 * 8];
    const f16x8 xv1 = *(const f16x8*)&XVb[(size_t)sc1 * N + k0 + sh0 * 8];
    const int nb = k0 + nsub * 16 + quad * 4;          // this thread's 4 n values
    const float4 r01 = *(const float4*)&rsB[nb];       // (max0,ri0,max1,ri1)
    const float4 r23 = *(const float4*)&rsB[nb + 2];   // (max2,ri2,max3,ri3)
    f32x4 e = (f32x4){0.f, 0.f, 0.f, 0.f};
    e = __builtin_amdgcn_mfma_f32_16x16x32_f16(aGn, bGm, e, 0, 0, 0);
    *(f16x8*)&XVs[bf][sc0 * 72 + sh0 * 8] = xv0;
    *(f16x8*)&XVs[bf][sc1 * 72 + sh0 * 8] = xv1;
    const float p0 = __expf(e[0] - r01.x + vmb) * r01.y;  // pad rows: ri=0 -> 0
    const float p1 = __expf(e[1] - r01.z + vmb) * r01.w;
    const float p2 = __expf(e[2] - r23.x + vmb) * r23.y;
    const float p3 = __expf(e[3] - r23.z + vmb) * r23.w;
    cs += (p0 + p1) + (p2 + p3);
    f16x4 pp = {(_Float16)p0, (_Float16)p1, (_Float16)p2, (_Float16)p3};
    *(f16x4*)&PsT[bf][(msub * 16 + lr) * 72 + nsub * 16 + quad * 4] = pp;
  };
  auto consume = [&](int bf) {
    const int c0 = w * 16;
    const f16x8 a0 = *(const f16x8*)&XVs[bf][(c0 + lr) * 72 + quad * 8];
    const f16x8 a1 = *(const f16x8*)&XVs[bf][(c0 + lr) * 72 + 32 + quad * 8];
    const f16x8 b00 = *(const f16x8*)&PsT[bf][lr * 72 + quad * 8];
    const f16x8 b01 = *(const f16x8*)&PsT[bf][lr * 72 + 32 + quad * 8];
    const f16x8 b10 = *(const f16x8*)&PsT[bf][(16 + lr) * 72 + quad * 8];
    const f16x8 b11 = *(const f16x8*)&PsT[bf][(16 + lr) * 72 + 32 + quad * 8];
    acc[0] = __builtin_amdgcn_mfma_f32_16x16x32_f16(a0, b00, acc[0], 0, 0, 0);
    acc[0] = __builtin_amdgcn_mfma_f32_16x16x32_f16(a1, b01, acc[0], 0, 0, 0);
    acc[1] = __builtin_amdgcn_mfma_f32_16x16x32_f16(a0, b10, acc[1], 0, 0, 0);
    acc[1] = __builtin_amdgcn_mfma_f32_16x16x32_f16(a1, b11, acc[1], 0, 0, 0);
  };

  if (ns > 0) produce(0, 0);
  __syncthreads();
  for (int it = 0; it < ns; it += 2) {
    if (it + 1 < ns) produce((it + 1) * 64, 1);
    consume(0);
    __syncthreads();
    if (it + 1 < ns) {
      if (it + 2 < ns) produce((it + 2) * 64, 0);
      consume(1);
      __syncthreads();
    }
  }
  // reduce cs across the 4 quads (n-quarters of column m=lr)
  cs += __shfl_xor(cs, 16, 64);
  cs += __shfl_xor(cs, 32, 64);
  if (quad == 0) colPart[nsub][msub * 16 + lr] = cs;
  __syncthreads();
  if (tid < 32)
    colS[tid] = colPart[0][tid] + colPart[1][tid] + colPart[2][tid] + colPart[3][tid];
  __syncthreads();
  const float ninvq = (float)(N - Nv) * 0.000244140625f;   // ninv/4096
  const float rdiv0 = 1.0f / (1e-9f + colS[lr] + ninvq);
  const float rdiv1 = 1.0f / (1e-9f + colS[16 + lr] + ninvq);
  const int cg = w * 16 + quad * 4;          // local channel base
  // ---- td tile -> LDS (reuse XVs[0]; PV loop is done) ----
  _Float16* TdS = &XVs[0][0];                // [32 m][136 c]
  {
    f16x4 t0, t1;
#pragma unroll
    for (int r = 0; r < 4; r++) {
      const float xadd = xvi[b * C + cg + r] * 0.000244140625f;  // xvInvSum/4096
      const size_t gi0 = (size_t)(b * C + cg + r) * N + m0 + lr;
      const size_t gi1 = gi0 + 16;
      t0[r] = (_Float16)(H[gi0] - (acc[0][r] + xadd) * rdiv0);
      t1[r] = (_Float16)(H[gi1] - (acc[1][r] + xadd) * rdiv1);
    }
    *(f16x4*)&TdS[lr * 136 + cg] = t0;
    *(f16x4*)&TdS[(16 + lr) * 136 + cg] = t1;
  }
  __syncthreads();
  // ---- fused wt-GEMM: out[o, m0..m0+31] = wt·td + bt; wave w owns o-tile w
  f32x4 acc2[2];
  acc2[0] = (f32x4){0.f, 0.f, 0.f, 0.f};
  acc2[1] = (f32x4){0.f, 0.f, 0.f, 0.f};
#pragma unroll
  for (int kc = 0; kc < 4; kc++) {
    const f16x8 aT = *(const f16x8*)&WFt[(size_t)(w * 16 + lr) * 128 + kc * 32 + quad * 8];
    const f16x8 bT0 = *(const f16x8*)&TdS[lr * 136 + kc * 32 + quad * 8];
    const f16x8 bT1 = *(const f16x8*)&TdS[(16 + lr) * 136 + kc * 32 + quad * 8];
    acc2[0] = __builtin_amdgcn_mfma_f32_16x16x32_f16(aT, bT0, acc2[0], 0, 0, 0);
    acc2[1] = __builtin_amdgcn_mfma_f32_16x16x32_f16(aT, bT1, acc2[1], 0, 0, 0);
  }
  const int oo = w * 16 + quad * 4;
  const int part = b * 128 + blockIdx.x;
#pragma unroll
  for (int r = 0; r < 4; r++) {
    const float v0 = acc2[0][r] + bt[oo + r];
    const float v1 = acc2[1][r] + bt[oo + r];
    const size_t go = (size_t)(b * C + oo + r) * N + m0 + lr;
    T2h[go] = (_Float16)v0;
    T2h[go + 16] = (_Float16)v1;
    float s = v0 + v1, q = v0 * v0 + v1 * v1;
    s += __shfl_xor(s, 1, 64); q += __shfl_xor(q, 1, 64);
    s += __shfl_xor(s, 2, 64); q += __shfl_xor(q, 2, 64);
    s += __shfl_xor(s, 4, 64); q += __shfl_xor(q, 4, 64);
    s += __shfl_xor(s, 8, 64); q += __shfl_xor(q, 8, 64);
    if (lr == 0) {
      bnpart[(oo + r) * 1024 + part] = s;
      bnpart[(oo + r) * 1024 + 512 + part] = q;
    }
  }
}

// ---------------------------------------------------------------------------
// Apply BN+ReLU (+residual, +write output slice).  T2 f16; PARTS partials.
// grid 2048, 256 thr.
// ---------------------------------------------------------------------------
template<bool RES, int PARTS>
__global__ __launch_bounds__(256) void k_apply(const _Float16* __restrict__ T2,
                                               const float* __restrict__ bnpart,
                                               const float* __restrict__ gamma,
                                               const float* __restrict__ beta,
                                               float* __restrict__ H,
                                               float* __restrict__ Out) {
  __shared__ float rs[4], rq[4], bc[2];
  const int tid = threadIdx.x;
  const int f = (blockIdx.x * 256 + tid) * 4;
  const int c = (blockIdx.x >> 2) & 127;
  float s, q;
  if (PARTS == 512) {
    s = bnpart[c * 1024 + tid] + bnpart[c * 1024 + 256 + tid];
    q = bnpart[c * 1024 + 512 + tid] + bnpart[c * 1024 + 768 + tid];
  } else {
    s = bnpart[c * 1024 + tid];
    q = bnpart[c * 1024 + 512 + tid];
  }
#pragma unroll
  for (int o = 1; o <= 32; o <<= 1) { s += __shfl_xor(s, o, 64); q += __shfl_xor(q, o, 64); }
  if ((tid & 63) == 0) { rs[tid >> 6] = s; rq[tid >> 6] = q; }
  __syncthreads();
  if (tid == 0) {
    const float st = rs[0] + rs[1] + rs[2] + rs[3];
    const float qt = rq[0] + rq[1] + rq[2] + rq[3];
    const float inv = 1.0f / (B * N);
    const float mean = st * inv;
    const float var = qt * inv - mean * mean;   // biased, like torch BN
    const float sc = gamma[c] * rsqrtf(var + 1e-5f);
    bc[0] = sc;
    bc[1] = beta[c] - mean * sc;
  }
  __syncthreads();
  const float sc = bc[0], sh = bc[1];
  const f16x4 t = *(const f16x4*)&T2[f];
  float4 r;
  r.x = fmaxf((float)t[0] * sc + sh, 0.f);
  r.y = fmaxf((float)t[1] * sc + sh, 0.f);
  r.z = fmaxf((float)t[2] * sc + sh, 0.f);
  r.w = fmaxf((float)t[3] * sc + sh, 0.f);
  if (RES) {
    const float4 h = *(const float4*)&H[f];
    r.x += h.x; r.y += h.y; r.z += h.z; r.w += h.w;
    *(float4*)&H[f] = r;
    const int b = f >> 19;                // f / (C*N)
    const int rem = f & (C * N - 1);      // c*N + n
    *(float4*)&Out[(size_t)b * (4 * C * N) + rem] = r;
  } else {
    *(float4*)&H[f] = r;
  }
}

// ---------------------------------------------------------------------------
extern "C" void kernel_launch(void* const* d_in, const int* in_sizes, int n_in,
                              void* d_out, int out_size, void* d_ws, size_t ws_size,
                              hipStream_t stream) {
  const float* x    = (const float*)d_in[0];
  const int*   mask = (const int*)  d_in[1];
  const float* w1   = (const float*)d_in[2];
  const float* g1   = (const float*)d_in[3];
  const float* b1   = (const float*)d_in[4];
  const float* w2   = (const float*)d_in[5];
  const float* g2   = (const float*)d_in[6];
  const float* b2   = (const float*)d_in[7];
  const float* wqk  = (const float*)d_in[8];
  const float* wv   = (const float*)d_in[9];
  const float* bv   = (const float*)d_in[10];
  const float* wt   = (const float*)d_in[11];
  const float* bt   = (const float*)d_in[12];
  const float* sg   = (const float*)d_in[13];
  const float* sb   = (const float*)d_in[14];
  float* out = (float*)d_out;

  char* p = (char*)d_ws;
  auto alloc = [&](size_t bytes) { char* r = p; p += (bytes + 255) & ~(size_t)255; return r; };
  float*    H      = (float*)   alloc((size_t)B * C * N * 4);
  _Float16* T2h    = (_Float16*)alloc((size_t)B * C * N * 2);
  _Float16* QT     = (_Float16*)alloc((size_t)B * N * 32 * 2);
  _Float16* QTc    = (_Float16*)alloc((size_t)B * N * 32 * 2);   // contiguous with
  _Float16* XVc    = (_Float16*)alloc((size_t)B * C * N * 2);    // XVc: one memset
  float2*   rowst  = (float2*)  alloc((size_t)B * N * 8);
  float*    bnpart = (float*)   alloc((size_t)C * 1024 * 4);
  int*      psum   = (int*)     alloc((size_t)B * N * 4);
  int*      nvb    = (int*)     alloc(256);
  float*    xvp    = (float*)   alloc((size_t)B * C * 128 * 4);
  float*    xvi    = (float*)   alloc((size_t)B * C * 4);
  _Float16* WF     = (_Float16*)alloc((size_t)180224 * 2);
  (void)ws_size;
  _Float16* wf1  = WF;
  _Float16* wf2  = WF + 16384;
  _Float16* wfv  = WF + 32768;
  _Float16* wft  = WF + 98304;
  _Float16* wfqk = WF + 163840;

  // ---- one-shot setup: weight convert, mask compaction, pad zeroing ----
  k_wcvt<<<176, 256, 0, stream>>>(w1, w2, wv, wt, wqk, WF);
  k_mask<<<B, 1024, 0, stream>>>(mask, psum, nvb);
  hipMemsetAsync(QTc, 0, (size_t)B * N * 32 * 2 + (size_t)B * C * N * 2, stream);

  // ---- stem: two conv1d(+BN+ReLU), MFMA, BN partials fused ----
  k_gwm<false, true, false><<<dim3(64, 2, B), 512, 0, stream>>>(wf1, x, nullptr, T2h, bnpart);
  k_apply<false, 256><<<2048, 256, 0, stream>>>(T2h, bnpart, g1, b1, H, nullptr);
  k_gwm<false, true, false><<<dim3(64, 2, B), 512, 0, stream>>>(wf2, H, nullptr, T2h, bnpart);
  k_apply<false, 256><<<2048, 256, 0, stream>>>(T2h, bnpart, g2, b2, H, nullptr);

  // ---- 4 chained offset-attention layers (flash-style, fused wt-GEMM) ----
  for (int L = 0; L < 4; L++) {
    k_qv<<<dim3(128, B), 256, 0, stream>>>(wfv + (size_t)L * 16384, wfqk + (size_t)L * 4096,
                                           H, bv + L * C, mask, psum, XVc, QT, QTc, xvp);
    k_sm<<<dim3(257, B), 512, 0, stream>>>(QTc, nvb, xvp, xvi, rowst);
    k_pv<<<dim3(128, B), 512, 0, stream>>>(QT, QTc, XVc, wft + (size_t)L * 16384, H, mask,
                                           rowst, nvb, xvi, bt + L * C, T2h, bnpart);
    k_apply<true, 512><<<2048, 256, 0, stream>>>(T2h, bnpart, sg + L * C, sb + L * C, H,
                                                 out + (size_t)L * C * N);
  }
}